// Round 7
// baseline (281.775 us; speedup 1.0000x reference)
//
#include <hip/hip_runtime.h>
#include <math.h>

#define N_NODES 100000
#define N_EDGES 1600000
#define D_IN 128
#define HIDDEN 128
#define D_OUT 40
#define EPSN 1e-12f

// bucket = dst >> 8 (256 nodes per bucket)
#define NBUCK 391                            // ceil(100000/256)
#define EPB 4096                             // edges per bhist block
#define NPART ((N_EDGES + EPB - 1) / EPB)    // 391
#define PEPB 4096                            // edges per bpart block
#define PNPART ((N_EDGES + PEPB - 1) / PEPB) // 391

#define SWZ1_TOTAL (8 * 8 * 4 * 16 * 8)   // 32768  (K=256, N=128)
#define SWZ2_TOTAL (4 * 8 * 4 * 16 * 8)   // 16384  (K=128, N=128: [g_l64|g_r64])
#define CASTB ((N_NODES * 16) / 256)      // 6250 blocks: fp32 -> fp16 (8 floats/thread)
#define SWZB ((SWZ1_TOTAL + SWZ2_TOTAL + 255) / 256)  // 192

typedef __attribute__((ext_vector_type(8))) _Float16 half8;
typedef __attribute__((ext_vector_type(4))) float float4v;

union H8 { half8 h; uint4 u; };

static __device__ inline unsigned short f2hbits(float f) {
    union { _Float16 h; unsigned short s; } u;
    u.h = (_Float16)f;
    return u.s;
}
static __device__ inline unsigned packh(float a, float b) {
    return (unsigned)f2hbits(a) | ((unsigned)f2hbits(b) << 16);
}
static __device__ inline float hlo(unsigned u) {
    union { unsigned short s; _Float16 h; } v;
    v.s = (unsigned short)(u & 0xffffu);
    return (float)v.h;
}
static __device__ inline float hhi(unsigned u) {
    union { unsigned short s; _Float16 h; } v;
    v.s = (unsigned short)(u >> 16);
    return (float)v.h;
}

// ---------------- prep: bhist + fp32->fp16 cast + weight swizzles (all fp16) ----------------
__global__ void prep_kernel(const int* __restrict__ dst, int* __restrict__ bucketCount,
                            const float* __restrict__ x, uint4* __restrict__ xh,
                            const float* __restrict__ Wl1, const float* __restrict__ Wr1,
                            const float* __restrict__ Wl2, const float* __restrict__ Wr2,
                            unsigned short* __restrict__ out1, unsigned short* __restrict__ out2) {
    __shared__ int h[NBUCK];
    int b = blockIdx.x, t = threadIdx.x;
    if (b < NPART) {
        for (int i = t; i < NBUCK; i += 256) h[i] = 0;
        __syncthreads();
        int es = b * EPB;
        int ee = min(es + EPB, N_EDGES);
        for (int i = es + t; i < ee; i += 256) atomicAdd(&h[dst[i] >> 8], 1);
        __syncthreads();
        for (int i = t; i < NBUCK; i += 256)
            if (h[i]) atomicAdd(&bucketCount[i], h[i]);
        return;
    }
    b -= NPART;
    if (b < CASTB) {
        // 8 floats/thread -> 8 fp16 (one uint4)
        int g = b * 256 + t;
        const float4* x4 = (const float4*)x;
        float4 lo = x4[2 * g], hi = x4[2 * g + 1];
        uint4 o;
        o.x = packh(lo.x, lo.y);
        o.y = packh(lo.z, lo.w);
        o.z = packh(hi.x, hi.y);
        o.w = packh(hi.z, hi.w);
        xh[g] = o;
        return;
    }
    b -= CASTB;
    {
        int idx = b * 256 + t;
        if (idx < SWZ1_TOTAL) {
            int j = idx & 7, l15 = (idx >> 3) & 15, quad = (idx >> 7) & 3;
            int rem = idx >> 9;
            int c = rem & 7, kt = rem >> 3;
            int k = kt * 32 + quad * 8 + j;
            int n = c * 16 + l15;
            float val = (k < 128) ? Wl1[k * HIDDEN + n] : Wr1[(k - 128) * HIDDEN + n];
            out1[idx] = f2hbits(val);
        } else if (idx < SWZ1_TOTAL + SWZ2_TOTAL) {
            idx -= SWZ1_TOTAL;
            int j = idx & 7, l15 = (idx >> 3) & 15, quad = (idx >> 7) & 3;
            int rem = idx >> 9;
            int c = rem & 7, kt = rem >> 3;
            int k = kt * 32 + quad * 8 + j;
            int n = c * 16 + l15;
            float val = 0.0f;
            if (n < D_OUT) val = Wl2[k * D_OUT + n];
            else if (n >= 64 && n < 64 + D_OUT) val = Wr2[k * D_OUT + (n - 64)];
            out2[idx] = f2hbits(val);
        }
    }
}

// ---------------- scan 391 bucket counts (one block) + zero the sortedSrc pad ----------------
__global__ void bscan_kernel(const int* __restrict__ bc, int* __restrict__ bstart,
                             int* __restrict__ cursor, int* __restrict__ sortedSrc) {
    __shared__ int s[256];
    int t = threadIdx.x;
    if (t < 64) sortedSrc[N_EDGES + t] = 0;   // pad for branch-free tails (runs before csr fill)
    int a = (2 * t < NBUCK) ? bc[2 * t] : 0;
    int b = (2 * t + 1 < NBUCK) ? bc[2 * t + 1] : 0;
    int tp = a + b;
    s[t] = tp;
    __syncthreads();
    for (int off = 1; off < 256; off <<= 1) {
        int tmp = (t >= off) ? s[t - off] : 0;
        __syncthreads();
        s[t] += tmp;
        __syncthreads();
    }
    int texcl = s[t] - tp;
    if (2 * t < NBUCK) { bstart[2 * t] = texcl; cursor[2 * t] = texcl; }
    if (2 * t + 1 < NBUCK) { bstart[2 * t + 1] = texcl + a; cursor[2 * t + 1] = texcl + a; }
    if (t == 255) bstart[NBUCK] = s[255];
}

// ---------------- partition edges into buckets (packed u32) ----------------
__global__ __launch_bounds__(512) void bpart_kernel(
    const int* __restrict__ src, const int* __restrict__ dst,
    int* __restrict__ cursor, unsigned* __restrict__ pairs) {
    __shared__ int h[NBUCK];
    __shared__ int base[NBUCK];
    int t = threadIdx.x;
    for (int i = t; i < NBUCK; i += 512) h[i] = 0;
    __syncthreads();
    int es = blockIdx.x * PEPB;
    int ee = min(es + PEPB, N_EDGES);
    for (int i = es + t; i < ee; i += 512) atomicAdd(&h[dst[i] >> 8], 1);
    __syncthreads();
    for (int i = t; i < NBUCK; i += 512) {
        int c = h[i];
        base[i] = c ? atomicAdd(&cursor[i], c) : 0;
    }
    __syncthreads();
    for (int i = t; i < NBUCK; i += 512) h[i] = 0;
    __syncthreads();
    for (int i = es + t; i < ee; i += 512) {
        int d = dst[i];
        int bk = d >> 8;
        int r = atomicAdd(&h[bk], 1);
        pairs[base[bk] + r] = ((unsigned)src[i] << 8) | (unsigned)(d & 255);
    }
}

// ---------------- per-bucket CSR finalize: count+scan+fill all in LDS ----------------
__global__ void csr_kernel(const unsigned* __restrict__ pairs, const int* __restrict__ bstart,
                           int* __restrict__ hist, int* __restrict__ rowStart,
                           int* __restrict__ sortedSrc) {
    __shared__ int cnt[256];
    __shared__ int sc[256];
    __shared__ int cur[256];
    int b = blockIdx.x, t = threadIdx.x;
    int es = bstart[b], ee = bstart[b + 1];
    cnt[t] = 0;
    __syncthreads();
    for (int i = es + t; i < ee; i += 256) atomicAdd(&cnt[pairs[i] & 255], 1);
    __syncthreads();
    int v = cnt[t];
    sc[t] = v;
    __syncthreads();
    for (int off = 1; off < 256; off <<= 1) {
        int tmp = (t >= off) ? sc[t - off] : 0;
        __syncthreads();
        sc[t] += tmp;
        __syncthreads();
    }
    int excl = sc[t] - v;
    int node = (b << 8) + t;
    if (node < N_NODES) {
        hist[node] = v;
        rowStart[node] = es + excl;
    }
    cur[t] = excl;
    __syncthreads();
    for (int i = es + t; i < ee; i += 256) {
        unsigned p = pairs[i];
        int r = atomicAdd(&cur[p & 255], 1);
        sortedSrc[es + r] = (int)(p >> 8);
    }
}

// ---------------- layer-1 gather-mean from fp16 table: one wave per node ----------------
// 4 edge-groups (g) x 16 lanes (sl, 16B uint4 chunks of the 256B fp16 row).
// Accumulate as half8: uint4 load + 4x v_pk_add_f16 per edge (no decode).
// Branch-free zero-masked tail (sortedSrc padded).
__global__ void agg_kernel(const uint4* __restrict__ xh,  // [N][16] uint4 (256B fp16 rows)
                           const int* __restrict__ sortedSrc,
                           const int* __restrict__ rowStart, const int* __restrict__ hist,
                           uint4* __restrict__ meanh) {
    int w = __builtin_amdgcn_readfirstlane((int)(threadIdx.x >> 6));
    int node = blockIdx.x * 4 + w;
    int lane = threadIdx.x & 63;
    int g = lane >> 4, sl = lane & 15;
    int s0 = __builtin_amdgcn_readfirstlane(rowStart[node]);
    int cnt = __builtin_amdgcn_readfirstlane(hist[node]);
    H8 acc;
    acc.u = (uint4){0u, 0u, 0u, 0u};
    int i = 0;
    for (; i + 16 <= cnt; i += 16) {
        int sA = sortedSrc[s0 + i + g];
        int sB = sortedSrc[s0 + i + 4 + g];
        int sC = sortedSrc[s0 + i + 8 + g];
        int sD = sortedSrc[s0 + i + 12 + g];
        H8 vA, vB, vC, vD;
        vA.u = xh[(size_t)sA * 16 + sl];
        vB.u = xh[(size_t)sB * 16 + sl];
        vC.u = xh[(size_t)sC * 16 + sl];
        vD.u = xh[(size_t)sD * 16 + sl];
        acc.h += vA.h;
        acc.h += vB.h;
        acc.h += vC.h;
        acc.h += vD.h;
    }
    int rem = cnt - i;   // uniform scalar, 0..15
    if (rem) {
        int i0 = s0 + i;
        int sA = sortedSrc[i0 + g];
        int sB = sortedSrc[i0 + 4 + g];
        int sC = sortedSrc[i0 + 8 + g];
        int sD = sortedSrc[i0 + 12 + g];
        H8 vA, vB, vC, vD;
        vA.u = xh[(size_t)sA * 16 + sl];
        vB.u = xh[(size_t)sB * 16 + sl];
        vC.u = xh[(size_t)sC * 16 + sl];
        vD.u = xh[(size_t)sD * 16 + sl];
        if (g >= rem)      vA.u = (uint4){0u, 0u, 0u, 0u};
        if (g + 4 >= rem)  vB.u = (uint4){0u, 0u, 0u, 0u};
        if (g + 8 >= rem)  vC.u = (uint4){0u, 0u, 0u, 0u};
        if (g + 12 >= rem) vD.u = (uint4){0u, 0u, 0u, 0u};
        acc.h += vA.h;
        acc.h += vB.h;
        acc.h += vC.h;
        acc.h += vD.h;
    }
    // reduce across the 4 edge-groups (lanes xor 16, 32) on packed u32
    {
        H8 t1;
        t1.u.x = __shfl_xor(acc.u.x, 16, 64);
        t1.u.y = __shfl_xor(acc.u.y, 16, 64);
        t1.u.z = __shfl_xor(acc.u.z, 16, 64);
        t1.u.w = __shfl_xor(acc.u.w, 16, 64);
        acc.h += t1.h;
        H8 t2;
        t2.u.x = __shfl_xor(acc.u.x, 32, 64);
        t2.u.y = __shfl_xor(acc.u.y, 32, 64);
        t2.u.z = __shfl_xor(acc.u.z, 32, 64);
        t2.u.w = __shfl_xor(acc.u.w, 32, 64);
        acc.h += t2.h;
    }
    if (g == 0) {
        float dinv = 1.0f / fmaxf((float)cnt, 1.0f);
        float f0 = (float)acc.h[0] * dinv, f1 = (float)acc.h[1] * dinv;
        float f2 = (float)acc.h[2] * dinv, f3 = (float)acc.h[3] * dinv;
        float f4 = (float)acc.h[4] * dinv, f5 = (float)acc.h[5] * dinv;
        float f6 = (float)acc.h[6] * dinv, f7 = (float)acc.h[7] * dinv;
        uint4 o;
        o.x = packh(f0, f1);
        o.y = packh(f2, f3);
        o.z = packh(f4, f5);
        o.w = packh(f6, f7);
        meanh[(size_t)node * 16 + sl] = o;
    }
}

// ---------------- layer-1 GEMM + norm + relu + layer-2 projection (2 f16 MFMA passes) ----------------
__global__ __launch_bounds__(256) void gemm1g_kernel(
    const unsigned short* __restrict__ meanh, const unsigned short* __restrict__ xh,
    const unsigned short* __restrict__ bswz1, const float* __restrict__ bias1,
    const unsigned short* __restrict__ bswz2,
    unsigned short* __restrict__ g_l, unsigned short* __restrict__ g_r) {
    __shared__ unsigned short hT[4][16][140];
    int tid = threadIdx.x;
    int w = __builtin_amdgcn_readfirstlane(tid >> 6);
    int lane = tid & 63;
    int l15 = lane & 15, quad = lane >> 4;
    int n0 = blockIdx.x * 64;
    int nodeA = n0 + w * 16 + l15;
    if (nodeA >= N_NODES) nodeA = N_NODES - 1;

    float4v acc[8];
#pragma unroll
    for (int c = 0; c < 8; c++) acc[c] = (float4v){0.f, 0.f, 0.f, 0.f};
#pragma unroll
    for (int kt = 0; kt < 8; kt++) {
        const unsigned short* ab = (kt < 4) ? meanh : xh;
        half8 a = *(const half8*)(ab + (size_t)nodeA * 128 + (kt & 3) * 32 + quad * 8);
#pragma unroll
        for (int c = 0; c < 8; c++) {
            half8 b = *(const half8*)(bswz1 + (((kt * 8 + c) * 4 + quad) * 16 + l15) * 8);
            acc[c] = __builtin_amdgcn_mfma_f32_16x16x32_f16(a, b, acc[c], 0, 0, 0);
        }
    }

    float v[8][4];
    float ss[4] = {0.f, 0.f, 0.f, 0.f};
#pragma unroll
    for (int c = 0; c < 8; c++) {
        float bi = bias1[c * 16 + l15];
#pragma unroll
        for (int r = 0; r < 4; r++) {
            float t = acc[c][r] + bi;
            v[c][r] = t;
            ss[r] += t * t;
        }
    }
#pragma unroll
    for (int r = 0; r < 4; r++)
        for (int off = 1; off < 16; off <<= 1) ss[r] += __shfl_xor(ss[r], off, 64);
#pragma unroll
    for (int r = 0; r < 4; r++) {
        float inv = 1.0f / fmaxf(sqrtf(ss[r]), EPSN);
#pragma unroll
        for (int c = 0; c < 8; c++) {
            hT[w][quad * 4 + r][c * 16 + l15] = f2hbits(fmaxf(v[c][r] * inv, 0.0f));
        }
    }

    float4v acc2[8];
#pragma unroll
    for (int c = 0; c < 8; c++) acc2[c] = (float4v){0.f, 0.f, 0.f, 0.f};
#pragma unroll
    for (int kt = 0; kt < 4; kt++) {
        half8 a = *(const half8*)&hT[w][l15][kt * 32 + quad * 8];
#pragma unroll
        for (int c = 0; c < 8; c++) {
            half8 b = *(const half8*)(bswz2 + (((kt * 8 + c) * 4 + quad) * 16 + l15) * 8);
            acc2[c] = __builtin_amdgcn_mfma_f32_16x16x32_f16(a, b, acc2[c], 0, 0, 0);
        }
    }
#pragma unroll
    for (int r = 0; r < 4; r++) {
        int node = n0 + w * 16 + quad * 4 + r;
        if (node < N_NODES) {
#pragma unroll
            for (int c = 0; c < 4; c++)
                g_l[(size_t)node * 64 + c * 16 + l15] = f2hbits(acc2[c][r]);
#pragma unroll
            for (int c = 4; c < 8; c++)
                g_r[(size_t)node * 64 + (c - 4) * 16 + l15] = f2hbits(acc2[c][r]);
        }
    }
}

// ---------------- layer 2 final: 4 nodes per wave, packed fp16 accumulate ----------------
__global__ void fused2h_kernel(const uint4* __restrict__ g_l4, const uint4* __restrict__ g_r4,
                               const int* __restrict__ sortedSrc,
                               const int* __restrict__ rowStart, const int* __restrict__ hist,
                               const float* __restrict__ bias, float* __restrict__ out) {
    int tid = threadIdx.x;
    int w = __builtin_amdgcn_readfirstlane(tid >> 6);
    int lane = tid & 63;
    int g = lane >> 4, q1 = (lane >> 3) & 1, sl = lane & 7;
    int node = blockIdx.x * 16 + w * 4 + g;   // N_NODES % 16 == 0
    int s0 = rowStart[node];
    int cnt = hist[node];
    H8 A;
    A.u = (uint4){0u, 0u, 0u, 0u};
    int i = 0;
    for (; i + 8 <= cnt; i += 8) {
        int sA = sortedSrc[s0 + i + q1];
        int sB = sortedSrc[s0 + i + 2 + q1];
        int sC = sortedSrc[s0 + i + 4 + q1];
        int sD = sortedSrc[s0 + i + 6 + q1];
        H8 vA, vB, vC, vD;
        vA.u = g_l4[(size_t)sA * 8 + sl];
        vB.u = g_l4[(size_t)sB * 8 + sl];
        vC.u = g_l4[(size_t)sC * 8 + sl];
        vD.u = g_l4[(size_t)sD * 8 + sl];
        A.h += vA.h;
        A.h += vB.h;
        A.h += vC.h;
        A.h += vD.h;
    }
    {
        int rem = cnt - i;   // 0..7
        int i0 = s0 + i;
        int sA = sortedSrc[i0 + q1];
        int sB = sortedSrc[i0 + 2 + q1];
        int sC = sortedSrc[i0 + 4 + q1];
        int sD = sortedSrc[i0 + 6 + q1];
        H8 vA, vB, vC, vD;
        vA.u = g_l4[(size_t)sA * 8 + sl];
        vB.u = g_l4[(size_t)sB * 8 + sl];
        vC.u = g_l4[(size_t)sC * 8 + sl];
        vD.u = g_l4[(size_t)sD * 8 + sl];
        if (q1 >= rem)     vA.u = (uint4){0u, 0u, 0u, 0u};
        if (q1 + 2 >= rem) vB.u = (uint4){0u, 0u, 0u, 0u};
        if (q1 + 4 >= rem) vC.u = (uint4){0u, 0u, 0u, 0u};
        if (q1 + 6 >= rem) vD.u = (uint4){0u, 0u, 0u, 0u};
        A.h += vA.h;
        A.h += vB.h;
        A.h += vC.h;
        A.h += vD.h;
    }
    // reduce across the 2 edge-groups (lanes xor 8) on packed u32
    {
        H8 t1;
        t1.u.x = __shfl_xor(A.u.x, 8, 64);
        t1.u.y = __shfl_xor(A.u.y, 8, 64);
        t1.u.z = __shfl_xor(A.u.z, 8, 64);
        t1.u.w = __shfl_xor(A.u.w, 8, 64);
        A.h += t1.h;
    }
    float a0 = (float)A.h[0], a1 = (float)A.h[1], a2 = (float)A.h[2], a3 = (float)A.h[3];
    float a4 = (float)A.h[4], a5 = (float)A.h[5], a6 = (float)A.h[6], a7 = (float)A.h[7];
    float dinv = 1.0f / fmaxf((float)cnt, 1.0f);
    uint4 gr = g_r4[(size_t)node * 8 + sl];
    bool valid = (sl < 5);
    float b0 = 0, b1 = 0, b2 = 0, b3 = 0, b4 = 0, b5 = 0, b6 = 0, b7 = 0;
    if (valid) {
        b0 = bias[sl * 8 + 0]; b1 = bias[sl * 8 + 1]; b2 = bias[sl * 8 + 2]; b3 = bias[sl * 8 + 3];
        b4 = bias[sl * 8 + 4]; b5 = bias[sl * 8 + 5]; b6 = bias[sl * 8 + 6]; b7 = bias[sl * 8 + 7];
    }
    float t0 = a0 * dinv + hlo(gr.x) + b0;
    float t1 = a1 * dinv + hhi(gr.x) + b1;
    float t2 = a2 * dinv + hlo(gr.y) + b2;
    float t3 = a3 * dinv + hhi(gr.y) + b3;
    float t4 = a4 * dinv + hlo(gr.z) + b4;
    float t5 = a5 * dinv + hhi(gr.z) + b5;
    float t6 = a6 * dinv + hlo(gr.w) + b6;
    float t7 = a7 * dinv + hhi(gr.w) + b7;
    float ssq = t0 * t0 + t1 * t1 + t2 * t2 + t3 * t3 + t4 * t4 + t5 * t5 + t6 * t6 + t7 * t7;
    ssq += __shfl_xor(ssq, 1, 64); ssq += __shfl_xor(ssq, 2, 64); ssq += __shfl_xor(ssq, 4, 64);
    float inv = 1.0f / fmaxf(sqrtf(ssq), EPSN);
    float v0 = t0 * inv, v1 = t1 * inv, v2 = t2 * inv, v3 = t3 * inv;
    float v4 = t4 * inv, v5 = t5 * inv, v6 = t6 * inv, v7 = t7 * inv;
    float m = valid ? fmaxf(fmaxf(fmaxf(v0, v1), fmaxf(v2, v3)),
                            fmaxf(fmaxf(v4, v5), fmaxf(v6, v7))) : -INFINITY;
    m = fmaxf(m, __shfl_xor(m, 1, 64));
    m = fmaxf(m, __shfl_xor(m, 2, 64));
    m = fmaxf(m, __shfl_xor(m, 4, 64));
    float se = 0.0f;
    if (valid) {
        se = expf(v0 - m) + expf(v1 - m) + expf(v2 - m) + expf(v3 - m) +
             expf(v4 - m) + expf(v5 - m) + expf(v6 - m) + expf(v7 - m);
    }
    se += __shfl_xor(se, 1, 64); se += __shfl_xor(se, 2, 64); se += __shfl_xor(se, 4, 64);
    float ls = logf(se) + m;
    if (q1 == 0 && valid) {
        float* o = out + (size_t)node * D_OUT + sl * 8;
        ((float4*)o)[0] = (float4){v0 - ls, v1 - ls, v2 - ls, v3 - ls};
        ((float4*)o)[1] = (float4){v4 - ls, v5 - ls, v6 - ls, v7 - ls};
    }
}

static inline size_t align256(size_t x) { return (x + 255) & ~(size_t)255; }

extern "C" void kernel_launch(void* const* d_in, const int* in_sizes, int n_in,
                              void* d_out, int out_size, void* d_ws, size_t ws_size,
                              hipStream_t stream) {
    const float* x   = (const float*)d_in[0];
    const int*   ei  = (const int*)d_in[1];
    const float* Wl1 = (const float*)d_in[2];
    const float* bl1 = (const float*)d_in[3];
    const float* Wr1 = (const float*)d_in[4];
    const float* Wl2 = (const float*)d_in[5];
    const float* bl2 = (const float*)d_in[6];
    const float* Wr2 = (const float*)d_in[7];
    float* out = (float*)d_out;

    const int* src = ei;
    const int* dst = ei + N_EDGES;

    char* ws = (char*)d_ws;
    size_t off = 0;
    int* bucketCount = (int*)(ws + off); off += align256((size_t)NBUCK * 4);
    int* bucketStart = (int*)(ws + off); off += align256((size_t)(NBUCK + 1) * 4);
    int* cursor      = (int*)(ws + off); off += align256((size_t)NBUCK * 4);
    int* hist        = (int*)(ws + off); off += align256((size_t)N_NODES * 4);
    int* rowStart    = (int*)(ws + off); off += align256((size_t)N_NODES * 4);
    unsigned* pairs  = (unsigned*)(ws + off); off += align256((size_t)N_EDGES * 4);
    int* sortedSrc   = (int*)(ws + off); off += align256((size_t)(N_EDGES + 64) * 4);
    unsigned* xh     = (unsigned*)(ws + off); off += align256((size_t)N_NODES * 128 * 2);
    unsigned* meanh  = (unsigned*)(ws + off); off += align256((size_t)N_NODES * 128 * 2);
    unsigned short* g_l = (unsigned short*)(ws + off); off += align256((size_t)N_NODES * 64 * 2);
    unsigned short* g_r = (unsigned short*)(ws + off); off += align256((size_t)N_NODES * 64 * 2);
    unsigned short* bswz1 = (unsigned short*)(ws + off); off += align256((size_t)SWZ1_TOTAL * 2);
    unsigned short* bswz2 = (unsigned short*)(ws + off); off += align256((size_t)SWZ2_TOTAL * 2);

    hipMemsetAsync(bucketCount, 0, (size_t)NBUCK * 4, stream);

    prep_kernel<<<NPART + CASTB + SWZB, 256, 0, stream>>>(
        dst, bucketCount, x, (uint4*)xh, Wl1, Wr1, Wl2, Wr2, bswz1, bswz2);
    bscan_kernel<<<1, 256, 0, stream>>>(bucketCount, bucketStart, cursor, sortedSrc);
    bpart_kernel<<<PNPART, 512, 0, stream>>>(src, dst, cursor, pairs);
    csr_kernel<<<NBUCK, 256, 0, stream>>>(pairs, bucketStart, hist, rowStart, sortedSrc);

    agg_kernel<<<N_NODES / 4, 256, 0, stream>>>((const uint4*)xh, sortedSrc, rowStart, hist,
                                                (uint4*)meanh);
    gemm1g_kernel<<<(N_NODES + 63) / 64, 256, 0, stream>>>(
        (const unsigned short*)meanh, (const unsigned short*)xh,
        bswz1, bl1, bswz2, g_l, g_r);
    fused2h_kernel<<<N_NODES / 16, 256, 0, stream>>>(
        (const uint4*)g_l, (const uint4*)g_r, sortedSrc, rowStart, hist, bl2, out);
}

// Round 8
// 267.112 us; speedup vs baseline: 1.0549x; 1.0549x over previous
//
#include <hip/hip_runtime.h>
#include <math.h>

#define N_NODES 100000
#define N_EDGES 1600000
#define D_IN 128
#define HIDDEN 128
#define D_OUT 40
#define EPSN 1e-12f

// bucket = dst >> 8 (256 nodes per bucket)
#define NBUCK 391                            // ceil(100000/256)
#define EPB 4096                             // edges per bhist block
#define NPART ((N_EDGES + EPB - 1) / EPB)    // 391
#define PEPB 4096                            // edges per bpart block
#define PNPART ((N_EDGES + PEPB - 1) / PEPB) // 391

#define SWZ1_TOTAL (8 * 8 * 4 * 16 * 8)   // 32768  (K=256, N=128)
#define SWZ2_TOTAL (4 * 8 * 4 * 16 * 8)   // 16384  (K=128, N=128: [g_l64|g_r64])
#define CASTB ((N_NODES * 16) / 256)      // 6250 blocks: fp32 -> fp16 + fp8 fused (8 floats/thread)
#define SWZB ((SWZ1_TOTAL + SWZ2_TOTAL + 255) / 256)  // 192

typedef __attribute__((ext_vector_type(8))) _Float16 half8;
typedef __attribute__((ext_vector_type(4))) float float4v;
typedef __attribute__((ext_vector_type(2))) float float2v;

union H8 { half8 h; uint4 u; };

static __device__ inline unsigned short f2hbits(float f) {
    union { _Float16 h; unsigned short s; } u;
    u.h = (_Float16)f;
    return u.s;
}
static __device__ inline unsigned packh(float a, float b) {
    return (unsigned)f2hbits(a) | ((unsigned)f2hbits(b) << 16);
}
static __device__ inline float hlo(unsigned u) {
    union { unsigned short s; _Float16 h; } v;
    v.s = (unsigned short)(u & 0xffffu);
    return (float)v.h;
}
static __device__ inline float hhi(unsigned u) {
    union { unsigned short s; _Float16 h; } v;
    v.s = (unsigned short)(u >> 16);
    return (float)v.h;
}

// ---------- fp8 e4m3 encode/decode: HW cvt when available, bit-trick fallback ----------
#if defined(__has_builtin)
#if __has_builtin(__builtin_amdgcn_cvt_pk_f32_fp8) && __has_builtin(__builtin_amdgcn_cvt_pk_fp8_f32)
#define HAVE_HW_FP8 1
#endif
#endif

static __device__ inline float2v fp8lo(unsigned u) {
#ifdef HAVE_HW_FP8
    return __builtin_amdgcn_cvt_pk_f32_fp8(u, false);
#else
    unsigned b0 = u & 0xffu, b1 = (u >> 8) & 0xffu;
    union { unsigned u; float f; } v0, v1;
    v0.u = ((b0 & 0x80u) << 24) | ((b0 & 0x7fu) << 20);
    v1.u = ((b1 & 0x80u) << 24) | ((b1 & 0x7fu) << 20);
    float2v r; r.x = v0.f * 0x1p+120f; r.y = v1.f * 0x1p+120f;
    return r;
#endif
}
static __device__ inline float2v fp8hi(unsigned u) {
#ifdef HAVE_HW_FP8
    return __builtin_amdgcn_cvt_pk_f32_fp8(u, true);
#else
    unsigned b0 = (u >> 16) & 0xffu, b1 = (u >> 24) & 0xffu;
    union { unsigned u; float f; } v0, v1;
    v0.u = ((b0 & 0x80u) << 24) | ((b0 & 0x7fu) << 20);
    v1.u = ((b1 & 0x80u) << 24) | ((b1 & 0x7fu) << 20);
    float2v r; r.x = v0.f * 0x1p+120f; r.y = v1.f * 0x1p+120f;
    return r;
#endif
}
#ifndef HAVE_HW_FP8
static __device__ inline unsigned enc1(float x) {
    union { float f; unsigned u; } v; v.f = x * 0x1p-120f;
    unsigned um = v.u & 0x7fffffffu;
    unsigned r = um + 0x7FFFFu + ((um >> 20) & 1u);
    return ((r >> 20) & 0x7fu) | ((v.u >> 24) & 0x80u);
}
#endif
static __device__ inline unsigned fp8pack(float f0, float f1, float f2, float f3) {
#ifdef HAVE_HW_FP8
    unsigned u = __builtin_amdgcn_cvt_pk_fp8_f32(f0, f1, 0u, false);
    u = __builtin_amdgcn_cvt_pk_fp8_f32(f2, f3, u, true);
    return u;
#else
    return enc1(f0) | (enc1(f1) << 8) | (enc1(f2) << 16) | (enc1(f3) << 24);
#endif
}

// ---------------- prep: bhist + fused fp16/fp8 cast + weight swizzles (fp16) ----------------
__global__ void prep_kernel(const int* __restrict__ dst, int* __restrict__ bucketCount,
                            const float* __restrict__ x, uint4* __restrict__ xh,
                            unsigned* __restrict__ xf8,
                            const float* __restrict__ Wl1, const float* __restrict__ Wr1,
                            const float* __restrict__ Wl2, const float* __restrict__ Wr2,
                            unsigned short* __restrict__ out1, unsigned short* __restrict__ out2) {
    __shared__ int h[NBUCK];
    int b = blockIdx.x, t = threadIdx.x;
    if (b < NPART) {
        for (int i = t; i < NBUCK; i += 256) h[i] = 0;
        __syncthreads();
        int es = b * EPB;
        int ee = min(es + EPB, N_EDGES);
        for (int i = es + t; i < ee; i += 256) atomicAdd(&h[dst[i] >> 8], 1);
        __syncthreads();
        for (int i = t; i < NBUCK; i += 256)
            if (h[i]) atomicAdd(&bucketCount[i], h[i]);
        return;
    }
    b -= NPART;
    if (b < CASTB) {
        // 8 floats/thread: one pass over x produces BOTH the fp16 and fp8 tables
        int g = b * 256 + t;
        const float4* x4 = (const float4*)x;
        float4 lo = x4[2 * g], hi = x4[2 * g + 1];
        uint4 o;
        o.x = packh(lo.x, lo.y);
        o.y = packh(lo.z, lo.w);
        o.z = packh(hi.x, hi.y);
        o.w = packh(hi.z, hi.w);
        xh[g] = o;
        uint2 o8;
        o8.x = fp8pack(lo.x, lo.y, lo.z, lo.w);
        o8.y = fp8pack(hi.x, hi.y, hi.z, hi.w);
        ((uint2*)xf8)[g] = o8;
        return;
    }
    b -= CASTB;
    {
        int idx = b * 256 + t;
        if (idx < SWZ1_TOTAL) {
            int j = idx & 7, l15 = (idx >> 3) & 15, quad = (idx >> 7) & 3;
            int rem = idx >> 9;
            int c = rem & 7, kt = rem >> 3;
            int k = kt * 32 + quad * 8 + j;
            int n = c * 16 + l15;
            float val = (k < 128) ? Wl1[k * HIDDEN + n] : Wr1[(k - 128) * HIDDEN + n];
            out1[idx] = f2hbits(val);
        } else if (idx < SWZ1_TOTAL + SWZ2_TOTAL) {
            idx -= SWZ1_TOTAL;
            int j = idx & 7, l15 = (idx >> 3) & 15, quad = (idx >> 7) & 3;
            int rem = idx >> 9;
            int c = rem & 7, kt = rem >> 3;
            int k = kt * 32 + quad * 8 + j;
            int n = c * 16 + l15;
            float val = 0.0f;
            if (n < D_OUT) val = Wl2[k * D_OUT + n];
            else if (n >= 64 && n < 64 + D_OUT) val = Wr2[k * D_OUT + (n - 64)];
            out2[idx] = f2hbits(val);
        }
    }
}

// ---------------- scan 391 bucket counts (one block) + zero the sortedSrc pad ----------------
__global__ void bscan_kernel(const int* __restrict__ bc, int* __restrict__ bstart,
                             int* __restrict__ cursor, int* __restrict__ sortedSrc) {
    __shared__ int s[256];
    int t = threadIdx.x;
    if (t < 64) sortedSrc[N_EDGES + t] = 0;   // pad for branch-free tails (runs before csr fill)
    int a = (2 * t < NBUCK) ? bc[2 * t] : 0;
    int b = (2 * t + 1 < NBUCK) ? bc[2 * t + 1] : 0;
    int tp = a + b;
    s[t] = tp;
    __syncthreads();
    for (int off = 1; off < 256; off <<= 1) {
        int tmp = (t >= off) ? s[t - off] : 0;
        __syncthreads();
        s[t] += tmp;
        __syncthreads();
    }
    int texcl = s[t] - tp;
    if (2 * t < NBUCK) { bstart[2 * t] = texcl; cursor[2 * t] = texcl; }
    if (2 * t + 1 < NBUCK) { bstart[2 * t + 1] = texcl + a; cursor[2 * t + 1] = texcl + a; }
    if (t == 255) bstart[NBUCK] = s[255];
}

// ---------------- partition edges into buckets (packed u32) ----------------
__global__ __launch_bounds__(512) void bpart_kernel(
    const int* __restrict__ src, const int* __restrict__ dst,
    int* __restrict__ cursor, unsigned* __restrict__ pairs) {
    __shared__ int h[NBUCK];
    __shared__ int base[NBUCK];
    int t = threadIdx.x;
    for (int i = t; i < NBUCK; i += 512) h[i] = 0;
    __syncthreads();
    int es = blockIdx.x * PEPB;
    int ee = min(es + PEPB, N_EDGES);
    for (int i = es + t; i < ee; i += 512) atomicAdd(&h[dst[i] >> 8], 1);
    __syncthreads();
    for (int i = t; i < NBUCK; i += 512) {
        int c = h[i];
        base[i] = c ? atomicAdd(&cursor[i], c) : 0;
    }
    __syncthreads();
    for (int i = t; i < NBUCK; i += 512) h[i] = 0;
    __syncthreads();
    for (int i = es + t; i < ee; i += 512) {
        int d = dst[i];
        int bk = d >> 8;
        int r = atomicAdd(&h[bk], 1);
        pairs[base[bk] + r] = ((unsigned)src[i] << 8) | (unsigned)(d & 255);
    }
}

// ---------------- per-bucket CSR finalize: count+scan+fill all in LDS ----------------
__global__ void csr_kernel(const unsigned* __restrict__ pairs, const int* __restrict__ bstart,
                           int* __restrict__ hist, int* __restrict__ rowStart,
                           int* __restrict__ sortedSrc) {
    __shared__ int cnt[256];
    __shared__ int sc[256];
    __shared__ int cur[256];
    int b = blockIdx.x, t = threadIdx.x;
    int es = bstart[b], ee = bstart[b + 1];
    cnt[t] = 0;
    __syncthreads();
    for (int i = es + t; i < ee; i += 256) atomicAdd(&cnt[pairs[i] & 255], 1);
    __syncthreads();
    int v = cnt[t];
    sc[t] = v;
    __syncthreads();
    for (int off = 1; off < 256; off <<= 1) {
        int tmp = (t >= off) ? sc[t - off] : 0;
        __syncthreads();
        sc[t] += tmp;
        __syncthreads();
    }
    int excl = sc[t] - v;
    int node = (b << 8) + t;
    if (node < N_NODES) {
        hist[node] = v;
        rowStart[node] = es + excl;
    }
    cur[t] = excl;
    __syncthreads();
    for (int i = es + t; i < ee; i += 256) {
        unsigned p = pairs[i];
        int r = atomicAdd(&cur[p & 255], 1);
        sortedSrc[es + r] = (int)(p >> 8);
    }
}

// ---------------- layer-1 gather-mean from fp8 table: one wave per node ----------------
// 4 edge-groups (g) x 16 lanes (sl) x 8 features; float2 accumulators -> v_pk_add_f32.
// fp8 rows (128B): half the gather bytes of fp16 (round-7 lesson: bytes beat decode cost).
// Branch-free zero-masked tail (sortedSrc padded). Output mean packed to fp16.
#define ACC2(v)                                                                   \
    { a[0] += fp8lo(v.x); a[1] += fp8hi(v.x);                                     \
      a[2] += fp8lo(v.y); a[3] += fp8hi(v.y); }

__global__ void agg_kernel(const uint2* __restrict__ xf8,  // [N][16] uint2 (128B fp8 rows)
                           const int* __restrict__ sortedSrc,
                           const int* __restrict__ rowStart, const int* __restrict__ hist,
                           uint2* __restrict__ meanh) {
    int w = __builtin_amdgcn_readfirstlane((int)(threadIdx.x >> 6));
    int node = blockIdx.x * 4 + w;
    int lane = threadIdx.x & 63;
    int g = lane >> 4, sl = lane & 15;
    int s0 = __builtin_amdgcn_readfirstlane(rowStart[node]);
    int cnt = __builtin_amdgcn_readfirstlane(hist[node]);
    float2v a[4];
#pragma unroll
    for (int e = 0; e < 4; e++) a[e] = (float2v){0.f, 0.f};
    int i = 0;
    for (; i + 16 <= cnt; i += 16) {
        int sA = sortedSrc[s0 + i + g];
        int sB = sortedSrc[s0 + i + 4 + g];
        int sC = sortedSrc[s0 + i + 8 + g];
        int sD = sortedSrc[s0 + i + 12 + g];
        uint2 vA = xf8[sA * 16 + sl];
        uint2 vB = xf8[sB * 16 + sl];
        uint2 vC = xf8[sC * 16 + sl];
        uint2 vD = xf8[sD * 16 + sl];
        ACC2(vA)
        ACC2(vB)
        ACC2(vC)
        ACC2(vD)
    }
    int rem = cnt - i;   // uniform scalar, 0..15
    if (rem) {
        int i0 = s0 + i;
        int sA = sortedSrc[i0 + g];
        int sB = sortedSrc[i0 + 4 + g];
        int sC = sortedSrc[i0 + 8 + g];
        int sD = sortedSrc[i0 + 12 + g];
        uint2 vA = xf8[sA * 16 + sl];
        uint2 vB = xf8[sB * 16 + sl];
        uint2 vC = xf8[sC * 16 + sl];
        uint2 vD = xf8[sD * 16 + sl];
        if (g >= rem)      { vA.x = 0u; vA.y = 0u; }
        if (g + 4 >= rem)  { vB.x = 0u; vB.y = 0u; }
        if (g + 8 >= rem)  { vC.x = 0u; vC.y = 0u; }
        if (g + 12 >= rem) { vD.x = 0u; vD.y = 0u; }
        ACC2(vA)
        ACC2(vB)
        ACC2(vC)
        ACC2(vD)
    }
    // reduce across the 4 edge-groups (lanes xor 16, 32)
#pragma unroll
    for (int e = 0; e < 4; e++) {
        a[e].x += __shfl_xor(a[e].x, 16, 64);
        a[e].y += __shfl_xor(a[e].y, 16, 64);
    }
#pragma unroll
    for (int e = 0; e < 4; e++) {
        a[e].x += __shfl_xor(a[e].x, 32, 64);
        a[e].y += __shfl_xor(a[e].y, 32, 64);
    }
    if (g == 0) {
        float dinv = 1.0f / fmaxf((float)cnt, 1.0f);
        uint2 o;
        o.x = packh(a[0].x * dinv, a[0].y * dinv);
        o.y = packh(a[1].x * dinv, a[1].y * dinv);
        uint2 o2;
        o2.x = packh(a[2].x * dinv, a[2].y * dinv);
        o2.y = packh(a[3].x * dinv, a[3].y * dinv);
        meanh[(size_t)node * 32 + sl * 2] = o;
        meanh[(size_t)node * 32 + sl * 2 + 1] = o2;
    }
}

// ---------------- layer-1 GEMM + norm + relu + layer-2 projection (2 f16 MFMA passes) ----------------
__global__ __launch_bounds__(256) void gemm1g_kernel(
    const unsigned short* __restrict__ meanh, const unsigned short* __restrict__ xh,
    const unsigned short* __restrict__ bswz1, const float* __restrict__ bias1,
    const unsigned short* __restrict__ bswz2,
    unsigned short* __restrict__ g_l, unsigned short* __restrict__ g_r) {
    __shared__ unsigned short hT[4][16][140];
    int tid = threadIdx.x;
    int w = __builtin_amdgcn_readfirstlane(tid >> 6);
    int lane = tid & 63;
    int l15 = lane & 15, quad = lane >> 4;
    int n0 = blockIdx.x * 64;
    int nodeA = n0 + w * 16 + l15;
    if (nodeA >= N_NODES) nodeA = N_NODES - 1;

    float4v acc[8];
#pragma unroll
    for (int c = 0; c < 8; c++) acc[c] = (float4v){0.f, 0.f, 0.f, 0.f};
#pragma unroll
    for (int kt = 0; kt < 8; kt++) {
        const unsigned short* ab = (kt < 4) ? meanh : xh;
        half8 a = *(const half8*)(ab + (size_t)nodeA * 128 + (kt & 3) * 32 + quad * 8);
#pragma unroll
        for (int c = 0; c < 8; c++) {
            half8 b = *(const half8*)(bswz1 + (((kt * 8 + c) * 4 + quad) * 16 + l15) * 8);
            acc[c] = __builtin_amdgcn_mfma_f32_16x16x32_f16(a, b, acc[c], 0, 0, 0);
        }
    }

    float v[8][4];
    float ss[4] = {0.f, 0.f, 0.f, 0.f};
#pragma unroll
    for (int c = 0; c < 8; c++) {
        float bi = bias1[c * 16 + l15];
#pragma unroll
        for (int r = 0; r < 4; r++) {
            float t = acc[c][r] + bi;
            v[c][r] = t;
            ss[r] += t * t;
        }
    }
#pragma unroll
    for (int r = 0; r < 4; r++)
        for (int off = 1; off < 16; off <<= 1) ss[r] += __shfl_xor(ss[r], off, 64);
#pragma unroll
    for (int r = 0; r < 4; r++) {
        float inv = 1.0f / fmaxf(sqrtf(ss[r]), EPSN);
#pragma unroll
        for (int c = 0; c < 8; c++) {
            hT[w][quad * 4 + r][c * 16 + l15] = f2hbits(fmaxf(v[c][r] * inv, 0.0f));
        }
    }

    float4v acc2[8];
#pragma unroll
    for (int c = 0; c < 8; c++) acc2[c] = (float4v){0.f, 0.f, 0.f, 0.f};
#pragma unroll
    for (int kt = 0; kt < 4; kt++) {
        half8 a = *(const half8*)&hT[w][l15][kt * 32 + quad * 8];
#pragma unroll
        for (int c = 0; c < 8; c++) {
            half8 b = *(const half8*)(bswz2 + (((kt * 8 + c) * 4 + quad) * 16 + l15) * 8);
            acc2[c] = __builtin_amdgcn_mfma_f32_16x16x32_f16(a, b, acc2[c], 0, 0, 0);
        }
    }
#pragma unroll
    for (int r = 0; r < 4; r++) {
        int node = n0 + w * 16 + quad * 4 + r;
        if (node < N_NODES) {
#pragma unroll
            for (int c = 0; c < 4; c++)
                g_l[(size_t)node * 64 + c * 16 + l15] = f2hbits(acc2[c][r]);
#pragma unroll
            for (int c = 4; c < 8; c++)
                g_r[(size_t)node * 64 + (c - 4) * 16 + l15] = f2hbits(acc2[c][r]);
        }
    }
}

// ---------------- layer 2 final: 4 nodes per wave, packed fp16 accumulate ----------------
__global__ void fused2h_kernel(const uint4* __restrict__ g_l4, const uint4* __restrict__ g_r4,
                               const int* __restrict__ sortedSrc,
                               const int* __restrict__ rowStart, const int* __restrict__ hist,
                               const float* __restrict__ bias, float* __restrict__ out) {
    int tid = threadIdx.x;
    int w = __builtin_amdgcn_readfirstlane(tid >> 6);
    int lane = tid & 63;
    int g = lane >> 4, q1 = (lane >> 3) & 1, sl = lane & 7;
    int node = blockIdx.x * 16 + w * 4 + g;   // N_NODES % 16 == 0
    int s0 = rowStart[node];
    int cnt = hist[node];
    H8 A;
    A.u = (uint4){0u, 0u, 0u, 0u};
    int i = 0;
    for (; i + 8 <= cnt; i += 8) {
        int sA = sortedSrc[s0 + i + q1];
        int sB = sortedSrc[s0 + i + 2 + q1];
        int sC = sortedSrc[s0 + i + 4 + q1];
        int sD = sortedSrc[s0 + i + 6 + q1];
        H8 vA, vB, vC, vD;
        vA.u = g_l4[(size_t)sA * 8 + sl];
        vB.u = g_l4[(size_t)sB * 8 + sl];
        vC.u = g_l4[(size_t)sC * 8 + sl];
        vD.u = g_l4[(size_t)sD * 8 + sl];
        A.h += vA.h;
        A.h += vB.h;
        A.h += vC.h;
        A.h += vD.h;
    }
    {
        int rem = cnt - i;   // 0..7
        int i0 = s0 + i;
        int sA = sortedSrc[i0 + q1];
        int sB = sortedSrc[i0 + 2 + q1];
        int sC = sortedSrc[i0 + 4 + q1];
        int sD = sortedSrc[i0 + 6 + q1];
        H8 vA, vB, vC, vD;
        vA.u = g_l4[(size_t)sA * 8 + sl];
        vB.u = g_l4[(size_t)sB * 8 + sl];
        vC.u = g_l4[(size_t)sC * 8 + sl];
        vD.u = g_l4[(size_t)sD * 8 + sl];
        if (q1 >= rem)     vA.u = (uint4){0u, 0u, 0u, 0u};
        if (q1 + 2 >= rem) vB.u = (uint4){0u, 0u, 0u, 0u};
        if (q1 + 4 >= rem) vC.u = (uint4){0u, 0u, 0u, 0u};
        if (q1 + 6 >= rem) vD.u = (uint4){0u, 0u, 0u, 0u};
        A.h += vA.h;
        A.h += vB.h;
        A.h += vC.h;
        A.h += vD.h;
    }
    // reduce across the 2 edge-groups (lanes xor 8) on packed u32
    {
        H8 t1;
        t1.u.x = __shfl_xor(A.u.x, 8, 64);
        t1.u.y = __shfl_xor(A.u.y, 8, 64);
        t1.u.z = __shfl_xor(A.u.z, 8, 64);
        t1.u.w = __shfl_xor(A.u.w, 8, 64);
        A.h += t1.h;
    }
    float a0 = (float)A.h[0], a1 = (float)A.h[1], a2 = (float)A.h[2], a3 = (float)A.h[3];
    float a4 = (float)A.h[4], a5 = (float)A.h[5], a6 = (float)A.h[6], a7 = (float)A.h[7];
    float dinv = 1.0f / fmaxf((float)cnt, 1.0f);
    uint4 gr = g_r4[(size_t)node * 8 + sl];
    bool valid = (sl < 5);
    float b0 = 0, b1 = 0, b2 = 0, b3 = 0, b4 = 0, b5 = 0, b6 = 0, b7 = 0;
    if (valid) {
        b0 = bias[sl * 8 + 0]; b1 = bias[sl * 8 + 1]; b2 = bias[sl * 8 + 2]; b3 = bias[sl * 8 + 3];
        b4 = bias[sl * 8 + 4]; b5 = bias[sl * 8 + 5]; b6 = bias[sl * 8 + 6]; b7 = bias[sl * 8 + 7];
    }
    float t0 = a0 * dinv + hlo(gr.x) + b0;
    float t1 = a1 * dinv + hhi(gr.x) + b1;
    float t2 = a2 * dinv + hlo(gr.y) + b2;
    float t3 = a3 * dinv + hhi(gr.y) + b3;
    float t4 = a4 * dinv + hlo(gr.z) + b4;
    float t5 = a5 * dinv + hhi(gr.z) + b5;
    float t6 = a6 * dinv + hlo(gr.w) + b6;
    float t7 = a7 * dinv + hhi(gr.w) + b7;
    float ssq = t0 * t0 + t1 * t1 + t2 * t2 + t3 * t3 + t4 * t4 + t5 * t5 + t6 * t6 + t7 * t7;
    ssq += __shfl_xor(ssq, 1, 64); ssq += __shfl_xor(ssq, 2, 64); ssq += __shfl_xor(ssq, 4, 64);
    float inv = 1.0f / fmaxf(sqrtf(ssq), EPSN);
    float v0 = t0 * inv, v1 = t1 * inv, v2 = t2 * inv, v3 = t3 * inv;
    float v4 = t4 * inv, v5 = t5 * inv, v6 = t6 * inv, v7 = t7 * inv;
    float m = valid ? fmaxf(fmaxf(fmaxf(v0, v1), fmaxf(v2, v3)),
                            fmaxf(fmaxf(v4, v5), fmaxf(v6, v7))) : -INFINITY;
    m = fmaxf(m, __shfl_xor(m, 1, 64));
    m = fmaxf(m, __shfl_xor(m, 2, 64));
    m = fmaxf(m, __shfl_xor(m, 4, 64));
    float se = 0.0f;
    if (valid) {
        se = expf(v0 - m) + expf(v1 - m) + expf(v2 - m) + expf(v3 - m) +
             expf(v4 - m) + expf(v5 - m) + expf(v6 - m) + expf(v7 - m);
    }
    se += __shfl_xor(se, 1, 64); se += __shfl_xor(se, 2, 64); se += __shfl_xor(se, 4, 64);
    float ls = logf(se) + m;
    if (q1 == 0 && valid) {
        float* o = out + (size_t)node * D_OUT + sl * 8;
        ((float4*)o)[0] = (float4){v0 - ls, v1 - ls, v2 - ls, v3 - ls};
        ((float4*)o)[1] = (float4){v4 - ls, v5 - ls, v6 - ls, v7 - ls};
    }
}

static inline size_t align256(size_t x) { return (x + 255) & ~(size_t)255; }

extern "C" void kernel_launch(void* const* d_in, const int* in_sizes, int n_in,
                              void* d_out, int out_size, void* d_ws, size_t ws_size,
                              hipStream_t stream) {
    const float* x   = (const float*)d_in[0];
    const int*   ei  = (const int*)d_in[1];
    const float* Wl1 = (const float*)d_in[2];
    const float* bl1 = (const float*)d_in[3];
    const float* Wr1 = (const float*)d_in[4];
    const float* Wl2 = (const float*)d_in[5];
    const float* bl2 = (const float*)d_in[6];
    const float* Wr2 = (const float*)d_in[7];
    float* out = (float*)d_out;

    const int* src = ei;
    const int* dst = ei + N_EDGES;

    char* ws = (char*)d_ws;
    size_t off = 0;
    int* bucketCount = (int*)(ws + off); off += align256((size_t)NBUCK * 4);
    int* bucketStart = (int*)(ws + off); off += align256((size_t)(NBUCK + 1) * 4);
    int* cursor      = (int*)(ws + off); off += align256((size_t)NBUCK * 4);
    int* hist        = (int*)(ws + off); off += align256((size_t)N_NODES * 4);
    int* rowStart    = (int*)(ws + off); off += align256((size_t)N_NODES * 4);
    unsigned* pairs  = (unsigned*)(ws + off); off += align256((size_t)N_EDGES * 4);
    int* sortedSrc   = (int*)(ws + off); off += align256((size_t)(N_EDGES + 64) * 4);
    unsigned* xh     = (unsigned*)(ws + off); off += align256((size_t)N_NODES * 128 * 2);
    unsigned* xf8    = (unsigned*)(ws + off); off += align256((size_t)N_NODES * 128);
    unsigned* meanh  = (unsigned*)(ws + off); off += align256((size_t)N_NODES * 128 * 2);
    unsigned short* g_l = (unsigned short*)(ws + off); off += align256((size_t)N_NODES * 64 * 2);
    unsigned short* g_r = (unsigned short*)(ws + off); off += align256((size_t)N_NODES * 64 * 2);
    unsigned short* bswz1 = (unsigned short*)(ws + off); off += align256((size_t)SWZ1_TOTAL * 2);
    unsigned short* bswz2 = (unsigned short*)(ws + off); off += align256((size_t)SWZ2_TOTAL * 2);

    hipMemsetAsync(bucketCount, 0, (size_t)NBUCK * 4, stream);

    prep_kernel<<<NPART + CASTB + SWZB, 256, 0, stream>>>(
        dst, bucketCount, x, (uint4*)xh, xf8, Wl1, Wr1, Wl2, Wr2, bswz1, bswz2);
    bscan_kernel<<<1, 256, 0, stream>>>(bucketCount, bucketStart, cursor, sortedSrc);
    bpart_kernel<<<PNPART, 512, 0, stream>>>(src, dst, cursor, pairs);
    csr_kernel<<<NBUCK, 256, 0, stream>>>(pairs, bucketStart, hist, rowStart, sortedSrc);

    agg_kernel<<<N_NODES / 4, 256, 0, stream>>>((const uint2*)xf8, sortedSrc, rowStart, hist,
                                                (uint2*)meanh);
    gemm1g_kernel<<<(N_NODES + 63) / 64, 256, 0, stream>>>(
        (const unsigned short*)meanh, (const unsigned short*)xh,
        bswz1, bl1, bswz2, g_l, g_r);
    fused2h_kernel<<<N_NODES / 16, 256, 0, stream>>>(
        (const uint4*)g_l, (const uint4*)g_r, sortedSrc, rowStart, hist, bl2, out);
}

// Round 10
// 258.573 us; speedup vs baseline: 1.0897x; 1.0330x over previous
//
#include <hip/hip_runtime.h>
#include <math.h>

#define N_NODES 100000
#define N_EDGES 1600000
#define D_IN 128
#define HIDDEN 128
#define D_OUT 40
#define EPSN 1e-12f

// bucket = dst >> 8 (256 nodes per bucket); fixed-capacity bucket regions
#define NBUCK 391                            // ceil(100000/256)
#define BUCKCAP 4608                         // mean 4096 + 8 sigma
#define PEPB 4096                            // edges per bpart block
#define PNPART ((N_EDGES + PEPB - 1) / PEPB) // 391

#define SWZ1_TOTAL (8 * 8 * 4 * 16 * 8)   // 32768  (K=256, N=128)
#define SWZ2_TOTAL (4 * 8 * 4 * 16 * 8)   // 16384  (K=128, N=128: [g_l64|g_r64])
#define CASTB ((N_NODES * 16) / 256)      // 6250 blocks: fp32 -> fp16 + fp8 fused (8 floats/thread)
#define SWZB ((SWZ1_TOTAL + SWZ2_TOTAL + 255) / 256)  // 192

typedef __attribute__((ext_vector_type(8))) _Float16 half8;
typedef __attribute__((ext_vector_type(4))) float float4v;
typedef __attribute__((ext_vector_type(2))) float float2v;

union H8 { half8 h; uint4 u; };

static __device__ inline unsigned short f2hbits(float f) {
    union { _Float16 h; unsigned short s; } u;
    u.h = (_Float16)f;
    return u.s;
}
static __device__ inline unsigned packh(float a, float b) {
    return (unsigned)f2hbits(a) | ((unsigned)f2hbits(b) << 16);
}
static __device__ inline float hlo(unsigned u) {
    union { unsigned short s; _Float16 h; } v;
    v.s = (unsigned short)(u & 0xffffu);
    return (float)v.h;
}
static __device__ inline float hhi(unsigned u) {
    union { unsigned short s; _Float16 h; } v;
    v.s = (unsigned short)(u >> 16);
    return (float)v.h;
}

// ---------- fp8 e4m3 encode/decode: HW cvt when available, bit-trick fallback ----------
#if defined(__has_builtin)
#if __has_builtin(__builtin_amdgcn_cvt_pk_f32_fp8) && __has_builtin(__builtin_amdgcn_cvt_pk_fp8_f32)
#define HAVE_HW_FP8 1
#endif
#endif

static __device__ inline float2v fp8lo(unsigned u) {
#ifdef HAVE_HW_FP8
    return __builtin_amdgcn_cvt_pk_f32_fp8(u, false);
#else
    unsigned b0 = u & 0xffu, b1 = (u >> 8) & 0xffu;
    union { unsigned u; float f; } v0, v1;
    v0.u = ((b0 & 0x80u) << 24) | ((b0 & 0x7fu) << 20);
    v1.u = ((b1 & 0x80u) << 24) | ((b1 & 0x7fu) << 20);
    float2v r; r.x = v0.f * 0x1p+120f; r.y = v1.f * 0x1p+120f;
    return r;
#endif
}
static __device__ inline float2v fp8hi(unsigned u) {
#ifdef HAVE_HW_FP8
    return __builtin_amdgcn_cvt_pk_f32_fp8(u, true);
#else
    unsigned b0 = (u >> 16) & 0xffu, b1 = (u >> 24) & 0xffu;
    union { unsigned u; float f; } v0, v1;
    v0.u = ((b0 & 0x80u) << 24) | ((b0 & 0x7fu) << 20);
    v1.u = ((b1 & 0x80u) << 24) | ((b1 & 0x7fu) << 20);
    float2v r; r.x = v0.f * 0x1p+120f; r.y = v1.f * 0x1p+120f;
    return r;
#endif
}
#ifndef HAVE_HW_FP8
static __device__ inline unsigned enc1(float x) {
    union { float f; unsigned u; } v; v.f = x * 0x1p-120f;
    unsigned um = v.u & 0x7fffffffu;
    unsigned r = um + 0x7FFFFu + ((um >> 20) & 1u);
    return ((r >> 20) & 0x7fu) | ((v.u >> 24) & 0x80u);
}
#endif
static __device__ inline unsigned fp8pack(float f0, float f1, float f2, float f3) {
#ifdef HAVE_HW_FP8
    unsigned u = __builtin_amdgcn_cvt_pk_fp8_f32(f0, f1, 0u, false);
    u = __builtin_amdgcn_cvt_pk_fp8_f32(f2, f3, u, true);
    return u;
#else
    return enc1(f0) | (enc1(f1) << 8) | (enc1(f2) << 16) | (enc1(f3) << 24);
#endif
}

// ---------------- prep: fused fp16/fp8 cast + weight swizzles (no hist pass) ----------------
__global__ void prep_kernel(const float* __restrict__ x, uint4* __restrict__ xh,
                            unsigned* __restrict__ xf8,
                            const float* __restrict__ Wl1, const float* __restrict__ Wr1,
                            const float* __restrict__ Wl2, const float* __restrict__ Wr2,
                            unsigned short* __restrict__ out1, unsigned short* __restrict__ out2) {
    int b = blockIdx.x, t = threadIdx.x;
    if (b < CASTB) {
        // 8 floats/thread: one pass over x produces BOTH the fp16 and fp8 tables
        int g = b * 256 + t;
        const float4* x4 = (const float4*)x;
        float4 lo = x4[2 * g], hi = x4[2 * g + 1];
        uint4 o;
        o.x = packh(lo.x, lo.y);
        o.y = packh(lo.z, lo.w);
        o.z = packh(hi.x, hi.y);
        o.w = packh(hi.z, hi.w);
        xh[g] = o;
        uint2 o8;
        o8.x = fp8pack(lo.x, lo.y, lo.z, lo.w);
        o8.y = fp8pack(hi.x, hi.y, hi.z, hi.w);
        ((uint2*)xf8)[g] = o8;
        return;
    }
    b -= CASTB;
    {
        int idx = b * 256 + t;
        if (idx < SWZ1_TOTAL) {
            int j = idx & 7, l15 = (idx >> 3) & 15, quad = (idx >> 7) & 3;
            int rem = idx >> 9;
            int c = rem & 7, kt = rem >> 3;
            int k = kt * 32 + quad * 8 + j;
            int n = c * 16 + l15;
            float val = (k < 128) ? Wl1[k * HIDDEN + n] : Wr1[(k - 128) * HIDDEN + n];
            out1[idx] = f2hbits(val);
        } else if (idx < SWZ1_TOTAL + SWZ2_TOTAL) {
            idx -= SWZ1_TOTAL;
            int j = idx & 7, l15 = (idx >> 3) & 15, quad = (idx >> 7) & 3;
            int rem = idx >> 9;
            int c = rem & 7, kt = rem >> 3;
            int k = kt * 32 + quad * 8 + j;
            int n = c * 16 + l15;
            float val = 0.0f;
            if (n < D_OUT) val = Wl2[k * D_OUT + n];
            else if (n >= 64 && n < 64 + D_OUT) val = Wr2[k * D_OUT + (n - 64)];
            out2[idx] = f2hbits(val);
        }
    }
}

// ---------------- partition edges into fixed-capacity bucket regions ----------------
// No pre-scan needed: each block reserves via atomicAdd on the per-bucket cursor and
// scatters into region bk*BUCKCAP + offset.
__global__ __launch_bounds__(512) void bpart_kernel(
    const int* __restrict__ src, const int* __restrict__ dst,
    int* __restrict__ cursor, unsigned* __restrict__ pairs) {
    __shared__ int h[NBUCK];
    __shared__ int base[NBUCK];
    int t = threadIdx.x;
    for (int i = t; i < NBUCK; i += 512) h[i] = 0;
    __syncthreads();
    int es = blockIdx.x * PEPB;
    int ee = min(es + PEPB, N_EDGES);
    for (int i = es + t; i < ee; i += 512) atomicAdd(&h[dst[i] >> 8], 1);
    __syncthreads();
    for (int i = t; i < NBUCK; i += 512) {
        int c = h[i];
        base[i] = i * BUCKCAP + (c ? atomicAdd(&cursor[i], c) : 0);
    }
    __syncthreads();
    for (int i = t; i < NBUCK; i += 512) h[i] = 0;
    __syncthreads();
    for (int i = es + t; i < ee; i += 512) {
        int d = dst[i];
        int bk = d >> 8;
        int r = atomicAdd(&h[bk], 1);
        pairs[base[bk] + r] = ((unsigned)src[i] << 8) | (unsigned)(d & 255);
    }
}

// ---------------- per-bucket CSR finalize: count+scan+fill all in LDS ----------------
// sortedSrc entries are PRE-SCALED byte offsets (src<<7: both gather tables have 128B rows).
// Zeroes a 64-entry gap after the bucket fill (clamped to own region) for branch-free tails.
__global__ void csr_kernel(const unsigned* __restrict__ pairs, const int* __restrict__ bcnt,
                           int* __restrict__ hist, int* __restrict__ rowStart,
                           int* __restrict__ sortedSrc) {
    __shared__ int cnt[256];
    __shared__ int sc[256];
    __shared__ int cur[256];
    int b = blockIdx.x, t = threadIdx.x;
    int es = b * BUCKCAP;
    int ee = es + bcnt[b];
    cnt[t] = 0;
    __syncthreads();
    for (int i = es + t; i < ee; i += 256) atomicAdd(&cnt[pairs[i] & 255], 1);
    __syncthreads();
    int v = cnt[t];
    sc[t] = v;
    __syncthreads();
    for (int off = 1; off < 256; off <<= 1) {
        int tmp = (t >= off) ? sc[t - off] : 0;
        __syncthreads();
        sc[t] += tmp;
        __syncthreads();
    }
    int excl = sc[t] - v;
    int node = (b << 8) + t;
    if (node < N_NODES) {
        hist[node] = v;
        rowStart[node] = es + excl;
    }
    cur[t] = excl;
    __syncthreads();
    for (int i = es + t; i < ee; i += 256) {
        unsigned p = pairs[i];
        int r = atomicAdd(&cur[p & 255], 1);
        sortedSrc[es + r] = (int)((p >> 8) << 7);   // pre-scaled byte offset
    }
    // zero the tail-pad gap (no race: clamped to this bucket's own region; last bucket unclamped)
    if (t < 64 && (b == NBUCK - 1 || ee + t < es + BUCKCAP)) sortedSrc[ee + t] = 0;
}

// ---------------- layer-1 gather-mean from fp8 table: one wave per node ----------------
// 4 edge-groups (g) x 16 lanes (sl) x 8 features; float2 accumulators -> v_pk_add_f32.
// sortedSrc holds byte offsets: row addr = base + (off + sl*8), 32-bit voffset.
#define ACC2(v)                                                                   \
    { a[0] += fp8lo(v.x); a[1] += fp8hi(v.x);                                     \
      a[2] += fp8lo(v.y); a[3] += fp8hi(v.y); }

__global__ void agg_kernel(const uint2* __restrict__ xf8,  // [N] 128B fp8 rows
                           const int* __restrict__ sortedSrc,
                           const int* __restrict__ rowStart, const int* __restrict__ hist,
                           uint2* __restrict__ meanh) {
    const char* xb = (const char*)xf8;
    int w = __builtin_amdgcn_readfirstlane((int)(threadIdx.x >> 6));
    int node = blockIdx.x * 4 + w;
    int lane = threadIdx.x & 63;
    int g = lane >> 4, sl = lane & 15;
    unsigned sl8 = (unsigned)(sl * 8);
    int s0 = __builtin_amdgcn_readfirstlane(rowStart[node]);
    int cnt = __builtin_amdgcn_readfirstlane(hist[node]);
    float2v a[4];
#pragma unroll
    for (int e = 0; e < 4; e++) a[e] = (float2v){0.f, 0.f};
    int i = 0;
    for (; i + 16 <= cnt; i += 16) {
        int sA = sortedSrc[s0 + i + g];
        int sB = sortedSrc[s0 + i + 4 + g];
        int sC = sortedSrc[s0 + i + 8 + g];
        int sD = sortedSrc[s0 + i + 12 + g];
        uint2 vA = *(const uint2*)(xb + ((unsigned)sA + sl8));
        uint2 vB = *(const uint2*)(xb + ((unsigned)sB + sl8));
        uint2 vC = *(const uint2*)(xb + ((unsigned)sC + sl8));
        uint2 vD = *(const uint2*)(xb + ((unsigned)sD + sl8));
        ACC2(vA)
        ACC2(vB)
        ACC2(vC)
        ACC2(vD)
    }
    int rem = cnt - i;   // uniform scalar, 0..15
    if (rem) {
        int i0 = s0 + i;
        int sA = sortedSrc[i0 + g];
        int sB = sortedSrc[i0 + 4 + g];
        int sC = sortedSrc[i0 + 8 + g];
        int sD = sortedSrc[i0 + 12 + g];
        uint2 vA = *(const uint2*)(xb + ((unsigned)sA + sl8));
        uint2 vB = *(const uint2*)(xb + ((unsigned)sB + sl8));
        uint2 vC = *(const uint2*)(xb + ((unsigned)sC + sl8));
        uint2 vD = *(const uint2*)(xb + ((unsigned)sD + sl8));
        if (g >= rem)      { vA.x = 0u; vA.y = 0u; }
        if (g + 4 >= rem)  { vB.x = 0u; vB.y = 0u; }
        if (g + 8 >= rem)  { vC.x = 0u; vC.y = 0u; }
        if (g + 12 >= rem) { vD.x = 0u; vD.y = 0u; }
        ACC2(vA)
        ACC2(vB)
        ACC2(vC)
        ACC2(vD)
    }
    // reduce across the 4 edge-groups (lanes xor 16, 32)
#pragma unroll
    for (int e = 0; e < 4; e++) {
        a[e].x += __shfl_xor(a[e].x, 16, 64);
        a[e].y += __shfl_xor(a[e].y, 16, 64);
    }
#pragma unroll
    for (int e = 0; e < 4; e++) {
        a[e].x += __shfl_xor(a[e].x, 32, 64);
        a[e].y += __shfl_xor(a[e].y, 32, 64);
    }
    if (g == 0) {
        float dinv = 1.0f / fmaxf((float)cnt, 1.0f);
        uint2 o;
        o.x = packh(a[0].x * dinv, a[0].y * dinv);
        o.y = packh(a[1].x * dinv, a[1].y * dinv);
        uint2 o2;
        o2.x = packh(a[2].x * dinv, a[2].y * dinv);
        o2.y = packh(a[3].x * dinv, a[3].y * dinv);
        meanh[(size_t)node * 32 + sl * 2] = o;
        meanh[(size_t)node * 32 + sl * 2 + 1] = o2;
    }
}

// ---------------- layer-1 GEMM + norm + relu + layer-2 projection (2 f16 MFMA passes) ----------------
__global__ __launch_bounds__(256) void gemm1g_kernel(
    const unsigned short* __restrict__ meanh, const unsigned short* __restrict__ xh,
    const unsigned short* __restrict__ bswz1, const float* __restrict__ bias1,
    const unsigned short* __restrict__ bswz2,
    unsigned short* __restrict__ g_l, unsigned short* __restrict__ g_r) {
    __shared__ unsigned short hT[4][16][140];
    int tid = threadIdx.x;
    int w = __builtin_amdgcn_readfirstlane(tid >> 6);
    int lane = tid & 63;
    int l15 = lane & 15, quad = lane >> 4;
    int n0 = blockIdx.x * 64;
    int nodeA = n0 + w * 16 + l15;
    if (nodeA >= N_NODES) nodeA = N_NODES - 1;

    float4v acc[8];
#pragma unroll
    for (int c = 0; c < 8; c++) acc[c] = (float4v){0.f, 0.f, 0.f, 0.f};
#pragma unroll
    for (int kt = 0; kt < 8; kt++) {
        const unsigned short* ab = (kt < 4) ? meanh : xh;
        half8 a = *(const half8*)(ab + (size_t)nodeA * 128 + (kt & 3) * 32 + quad * 8);
#pragma unroll
        for (int c = 0; c < 8; c++) {
            half8 b = *(const half8*)(bswz1 + (((kt * 8 + c) * 4 + quad) * 16 + l15) * 8);
            acc[c] = __builtin_amdgcn_mfma_f32_16x16x32_f16(a, b, acc[c], 0, 0, 0);
        }
    }

    float v[8][4];
    float ss[4] = {0.f, 0.f, 0.f, 0.f};
#pragma unroll
    for (int c = 0; c < 8; c++) {
        float bi = bias1[c * 16 + l15];
#pragma unroll
        for (int r = 0; r < 4; r++) {
            float t = acc[c][r] + bi;
            v[c][r] = t;
            ss[r] += t * t;
        }
    }
#pragma unroll
    for (int r = 0; r < 4; r++)
        for (int off = 1; off < 16; off <<= 1) ss[r] += __shfl_xor(ss[r], off, 64);
#pragma unroll
    for (int r = 0; r < 4; r++) {
        float inv = 1.0f / fmaxf(sqrtf(ss[r]), EPSN);
#pragma unroll
        for (int c = 0; c < 8; c++) {
            hT[w][quad * 4 + r][c * 16 + l15] = f2hbits(fmaxf(v[c][r] * inv, 0.0f));
        }
    }

    float4v acc2[8];
#pragma unroll
    for (int c = 0; c < 8; c++) acc2[c] = (float4v){0.f, 0.f, 0.f, 0.f};
#pragma unroll
    for (int kt = 0; kt < 4; kt++) {
        half8 a = *(const half8*)&hT[w][l15][kt * 32 + quad * 8];
#pragma unroll
        for (int c = 0; c < 8; c++) {
            half8 b = *(const half8*)(bswz2 + (((kt * 8 + c) * 4 + quad) * 16 + l15) * 8);
            acc2[c] = __builtin_amdgcn_mfma_f32_16x16x32_f16(a, b, acc2[c], 0, 0, 0);
        }
    }
#pragma unroll
    for (int r = 0; r < 4; r++) {
        int node = n0 + w * 16 + quad * 4 + r;
        if (node < N_NODES) {
#pragma unroll
            for (int c = 0; c < 4; c++)
                g_l[(size_t)node * 64 + c * 16 + l15] = f2hbits(acc2[c][r]);
#pragma unroll
            for (int c = 4; c < 8; c++)
                g_r[(size_t)node * 64 + (c - 4) * 16 + l15] = f2hbits(acc2[c][r]);
        }
    }
}

// ---------------- layer 2 final: 4 nodes per wave, packed fp16 accumulate ----------------
// sortedSrc byte offsets: g_l row addr = base + (off + sl*16), 32-bit voffset.
__global__ void fused2h_kernel(const uint4* __restrict__ g_l4, const uint4* __restrict__ g_r4,
                               const int* __restrict__ sortedSrc,
                               const int* __restrict__ rowStart, const int* __restrict__ hist,
                               const float* __restrict__ bias, float* __restrict__ out) {
    const char* gb = (const char*)g_l4;
    int tid = threadIdx.x;
    int w = __builtin_amdgcn_readfirstlane(tid >> 6);
    int lane = tid & 63;
    int g = lane >> 4, q1 = (lane >> 3) & 1, sl = lane & 7;
    unsigned sl16 = (unsigned)(sl * 16);
    int node = blockIdx.x * 16 + w * 4 + g;   // N_NODES % 16 == 0
    int s0 = rowStart[node];
    int cnt = hist[node];
    H8 A;
    A.u = (uint4){0u, 0u, 0u, 0u};
    int i = 0;
    for (; i + 8 <= cnt; i += 8) {
        int sA = sortedSrc[s0 + i + q1];
        int sB = sortedSrc[s0 + i + 2 + q1];
        int sC = sortedSrc[s0 + i + 4 + q1];
        int sD = sortedSrc[s0 + i + 6 + q1];
        H8 vA, vB, vC, vD;
        vA.u = *(const uint4*)(gb + ((unsigned)sA + sl16));
        vB.u = *(const uint4*)(gb + ((unsigned)sB + sl16));
        vC.u = *(const uint4*)(gb + ((unsigned)sC + sl16));
        vD.u = *(const uint4*)(gb + ((unsigned)sD + sl16));
        A.h += vA.h;
        A.h += vB.h;
        A.h += vC.h;
        A.h += vD.h;
    }
    {
        int rem = cnt - i;   // 0..7
        int i0 = s0 + i;
        int sA = sortedSrc[i0 + q1];
        int sB = sortedSrc[i0 + 2 + q1];
        int sC = sortedSrc[i0 + 4 + q1];
        int sD = sortedSrc[i0 + 6 + q1];
        H8 vA, vB, vC, vD;
        vA.u = *(const uint4*)(gb + ((unsigned)sA + sl16));
        vB.u = *(const uint4*)(gb + ((unsigned)sB + sl16));
        vC.u = *(const uint4*)(gb + ((unsigned)sC + sl16));
        vD.u = *(const uint4*)(gb + ((unsigned)sD + sl16));
        if (q1 >= rem)     vA.u = (uint4){0u, 0u, 0u, 0u};
        if (q1 + 2 >= rem) vB.u = (uint4){0u, 0u, 0u, 0u};
        if (q1 + 4 >= rem) vC.u = (uint4){0u, 0u, 0u, 0u};
        if (q1 + 6 >= rem) vD.u = (uint4){0u, 0u, 0u, 0u};
        A.h += vA.h;
        A.h += vB.h;
        A.h += vC.h;
        A.h += vD.h;
    }
    // reduce across the 2 edge-groups (lanes xor 8) on packed u32
    {
        H8 t1;
        t1.u.x = __shfl_xor(A.u.x, 8, 64);
        t1.u.y = __shfl_xor(A.u.y, 8, 64);
        t1.u.z = __shfl_xor(A.u.z, 8, 64);
        t1.u.w = __shfl_xor(A.u.w, 8, 64);
        A.h += t1.h;
    }
    float a0 = (float)A.h[0], a1 = (float)A.h[1], a2 = (float)A.h[2], a3 = (float)A.h[3];
    float a4 = (float)A.h[4], a5 = (float)A.h[5], a6 = (float)A.h[6], a7 = (float)A.h[7];
    float dinv = 1.0f / fmaxf((float)cnt, 1.0f);
    uint4 gr = g_r4[(size_t)node * 8 + sl];
    bool valid = (sl < 5);
    float b0 = 0, b1 = 0, b2 = 0, b3 = 0, b4 = 0, b5 = 0, b6 = 0, b7 = 0;
    if (valid) {
        b0 = bias[sl * 8 + 0]; b1 = bias[sl * 8 + 1]; b2 = bias[sl * 8 + 2]; b3 = bias[sl * 8 + 3];
        b4 = bias[sl * 8 + 4]; b5 = bias[sl * 8 + 5]; b6 = bias[sl * 8 + 6]; b7 = bias[sl * 8 + 7];
    }
    float t0 = a0 * dinv + hlo(gr.x) + b0;
    float t1 = a1 * dinv + hhi(gr.x) + b1;
    float t2 = a2 * dinv + hlo(gr.y) + b2;
    float t3 = a3 * dinv + hhi(gr.y) + b3;
    float t4 = a4 * dinv + hlo(gr.z) + b4;
    float t5 = a5 * dinv + hhi(gr.z) + b5;
    float t6 = a6 * dinv + hlo(gr.w) + b6;
    float t7 = a7 * dinv + hhi(gr.w) + b7;
    float ssq = t0 * t0 + t1 * t1 + t2 * t2 + t3 * t3 + t4 * t4 + t5 * t5 + t6 * t6 + t7 * t7;
    ssq += __shfl_xor(ssq, 1, 64); ssq += __shfl_xor(ssq, 2, 64); ssq += __shfl_xor(ssq, 4, 64);
    float inv = 1.0f / fmaxf(sqrtf(ssq), EPSN);
    float v0 = t0 * inv, v1 = t1 * inv, v2 = t2 * inv, v3 = t3 * inv;
    float v4 = t4 * inv, v5 = t5 * inv, v6 = t6 * inv, v7 = t7 * inv;
    float m = valid ? fmaxf(fmaxf(fmaxf(v0, v1), fmaxf(v2, v3)),
                            fmaxf(fmaxf(v4, v5), fmaxf(v6, v7))) : -INFINITY;
    m = fmaxf(m, __shfl_xor(m, 1, 64));
    m = fmaxf(m, __shfl_xor(m, 2, 64));
    m = fmaxf(m, __shfl_xor(m, 4, 64));
    float se = 0.0f;
    if (valid) {
        se = expf(v0 - m) + expf(v1 - m) + expf(v2 - m) + expf(v3 - m) +
             expf(v4 - m) + expf(v5 - m) + expf(v6 - m) + expf(v7 - m);
    }
    se += __shfl_xor(se, 1, 64); se += __shfl_xor(se, 2, 64); se += __shfl_xor(se, 4, 64);
    float ls = logf(se) + m;
    if (q1 == 0 && valid) {
        float* o = out + (size_t)node * D_OUT + sl * 8;
        ((float4*)o)[0] = (float4){v0 - ls, v1 - ls, v2 - ls, v3 - ls};
        ((float4*)o)[1] = (float4){v4 - ls, v5 - ls, v6 - ls, v7 - ls};
    }
}

static inline size_t align256(size_t x) { return (x + 255) & ~(size_t)255; }

extern "C" void kernel_launch(void* const* d_in, const int* in_sizes, int n_in,
                              void* d_out, int out_size, void* d_ws, size_t ws_size,
                              hipStream_t stream) {
    const float* x   = (const float*)d_in[0];
    const int*   ei  = (const int*)d_in[1];
    const float* Wl1 = (const float*)d_in[2];
    const float* bl1 = (const float*)d_in[3];
    const float* Wr1 = (const float*)d_in[4];
    const float* Wl2 = (const float*)d_in[5];
    const float* bl2 = (const float*)d_in[6];
    const float* Wr2 = (const float*)d_in[7];
    float* out = (float*)d_out;

    const int* src = ei;
    const int* dst = ei + N_EDGES;

    char* ws = (char*)d_ws;
    size_t off = 0;
    int* cursor      = (int*)(ws + off); off += align256((size_t)NBUCK * 4);
    int* hist        = (int*)(ws + off); off += align256((size_t)N_NODES * 4);
    int* rowStart    = (int*)(ws + off); off += align256((size_t)N_NODES * 4);
    unsigned* pairs  = (unsigned*)(ws + off); off += align256((size_t)NBUCK * BUCKCAP * 4);
    int* sortedSrc   = (int*)(ws + off); off += align256(((size_t)NBUCK * BUCKCAP + 64) * 4);
    unsigned* xh     = (unsigned*)(ws + off); off += align256((size_t)N_NODES * 128 * 2);
    unsigned* xf8    = (unsigned*)(ws + off); off += align256((size_t)N_NODES * 128);
    unsigned* meanh  = (unsigned*)(ws + off); off += align256((size_t)N_NODES * 128 * 2);
    unsigned short* g_l = (unsigned short*)(ws + off); off += align256((size_t)N_NODES * 64 * 2);
    unsigned short* g_r = (unsigned short*)(ws + off); off += align256((size_t)N_NODES * 64 * 2);
    unsigned short* bswz1 = (unsigned short*)(ws + off); off += align256((size_t)SWZ1_TOTAL * 2);
    unsigned short* bswz2 = (unsigned short*)(ws + off); off += align256((size_t)SWZ2_TOTAL * 2);

    hipMemsetAsync(cursor, 0, (size_t)NBUCK * 4, stream);

    prep_kernel<<<CASTB + SWZB, 256, 0, stream>>>(
        x, (uint4*)xh, xf8, Wl1, Wr1, Wl2, Wr2, bswz1, bswz2);
    bpart_kernel<<<PNPART, 512, 0, stream>>>(src, dst, cursor, pairs);
    csr_kernel<<<NBUCK, 256, 0, stream>>>(pairs, cursor, hist, rowStart, sortedSrc);

    agg_kernel<<<N_NODES / 4, 256, 0, stream>>>((const uint2*)xf8, sortedSrc, rowStart, hist,
                                                (uint2*)meanh);
    gemm1g_kernel<<<(N_NODES + 63) / 64, 256, 0, stream>>>(
        (const unsigned short*)meanh, (const unsigned short*)xh,
        bswz1, bl1, bswz2, g_l, g_r);
    fused2h_kernel<<<N_NODES / 16, 256, 0, stream>>>(
        (const uint4*)g_l, (const uint4*)g_r, sortedSrc, rowStart, hist, bl2, out);
}

// Round 11
// 252.143 us; speedup vs baseline: 1.1175x; 1.0255x over previous
//
#include <hip/hip_runtime.h>
#include <math.h>

#define N_NODES 100000
#define N_EDGES 1600000
#define D_IN 128
#define HIDDEN 128
#define D_OUT 40
#define EPSN 1e-12f

// bucket = dst >> 8 (256 nodes per bucket); fixed-capacity bucket regions
#define NBUCK 391                            // ceil(100000/256)
#define BUCKCAP 4608                         // mean 4096 + 8 sigma
#define PEPB 4096                            // edges per bpart block
#define PNPART ((N_EDGES + PEPB - 1) / PEPB) // 391

#define SWZ1_TOTAL (8 * 8 * 4 * 16 * 8)   // 32768  (K=256, N=128)
#define SWZ2_TOTAL (4 * 8 * 4 * 16 * 8)   // 16384  (K=128, N=128: [g_l64|g_r64])
#define CASTB ((N_NODES * 16) / 512)      // 3125 blocks: fp32 -> fp16 + fp8 fused (8 floats/thread, 512 thr)
#define SWZB ((SWZ1_TOTAL + SWZ2_TOTAL) / 512)  // 96 (exact)

typedef __attribute__((ext_vector_type(8))) _Float16 half8;
typedef __attribute__((ext_vector_type(4))) float float4v;
typedef __attribute__((ext_vector_type(2))) float float2v;

union H8 { half8 h; uint4 u; };

static __device__ inline unsigned short f2hbits(float f) {
    union { _Float16 h; unsigned short s; } u;
    u.h = (_Float16)f;
    return u.s;
}
static __device__ inline unsigned packh(float a, float b) {
    return (unsigned)f2hbits(a) | ((unsigned)f2hbits(b) << 16);
}
static __device__ inline float hlo(unsigned u) {
    union { unsigned short s; _Float16 h; } v;
    v.s = (unsigned short)(u & 0xffffu);
    return (float)v.h;
}
static __device__ inline float hhi(unsigned u) {
    union { unsigned short s; _Float16 h; } v;
    v.s = (unsigned short)(u >> 16);
    return (float)v.h;
}

// ---------- fp8 e4m3 encode/decode: HW cvt when available, bit-trick fallback ----------
#if defined(__has_builtin)
#if __has_builtin(__builtin_amdgcn_cvt_pk_f32_fp8) && __has_builtin(__builtin_amdgcn_cvt_pk_fp8_f32)
#define HAVE_HW_FP8 1
#endif
#endif

static __device__ inline float2v fp8lo(unsigned u) {
#ifdef HAVE_HW_FP8
    return __builtin_amdgcn_cvt_pk_f32_fp8(u, false);
#else
    unsigned b0 = u & 0xffu, b1 = (u >> 8) & 0xffu;
    union { unsigned u; float f; } v0, v1;
    v0.u = ((b0 & 0x80u) << 24) | ((b0 & 0x7fu) << 20);
    v1.u = ((b1 & 0x80u) << 24) | ((b1 & 0x7fu) << 20);
    float2v r; r.x = v0.f * 0x1p+120f; r.y = v1.f * 0x1p+120f;
    return r;
#endif
}
static __device__ inline float2v fp8hi(unsigned u) {
#ifdef HAVE_HW_FP8
    return __builtin_amdgcn_cvt_pk_f32_fp8(u, true);
#else
    unsigned b0 = (u >> 16) & 0xffu, b1 = (u >> 24) & 0xffu;
    union { unsigned u; float f; } v0, v1;
    v0.u = ((b0 & 0x80u) << 24) | ((b0 & 0x7fu) << 20);
    v1.u = ((b1 & 0x80u) << 24) | ((b1 & 0x7fu) << 20);
    float2v r; r.x = v0.f * 0x1p+120f; r.y = v1.f * 0x1p+120f;
    return r;
#endif
}
#ifndef HAVE_HW_FP8
static __device__ inline unsigned enc1(float x) {
    union { float f; unsigned u; } v; v.f = x * 0x1p-120f;
    unsigned um = v.u & 0x7fffffffu;
    unsigned r = um + 0x7FFFFu + ((um >> 20) & 1u);
    return ((r >> 20) & 0x7fu) | ((v.u >> 24) & 0x80u);
}
#endif
static __device__ inline unsigned fp8pack(float f0, float f1, float f2, float f3) {
#ifdef HAVE_HW_FP8
    unsigned u = __builtin_amdgcn_cvt_pk_fp8_f32(f0, f1, 0u, false);
    u = __builtin_amdgcn_cvt_pk_fp8_f32(f2, f3, u, true);
    return u;
#else
    return enc1(f0) | (enc1(f1) << 8) | (enc1(f2) << 16) | (enc1(f3) << 24);
#endif
}

// ---------------- fused prep + bpart: independent stages co-scheduled ----------------
// Block roles: [0, PNPART) = edge partition (LDS-atomic heavy);
// [PNPART, +CASTB) = fp32->fp16/fp8 cast (HBM-BW heavy);
// [+CASTB, +SWZB) = weight swizzles. Complementary resources overlap on the CUs.
__global__ __launch_bounds__(512) void prep_bpart_kernel(
    const int* __restrict__ src, const int* __restrict__ dst,
    int* __restrict__ cursor, unsigned* __restrict__ pairs,
    const float* __restrict__ x, uint4* __restrict__ xh, unsigned* __restrict__ xf8,
    const float* __restrict__ Wl1, const float* __restrict__ Wr1,
    const float* __restrict__ Wl2, const float* __restrict__ Wr2,
    unsigned short* __restrict__ out1, unsigned short* __restrict__ out2) {
    __shared__ int h[NBUCK];
    __shared__ int base[NBUCK];
    int b = blockIdx.x, t = threadIdx.x;
    if (b < PNPART) {
        for (int i = t; i < NBUCK; i += 512) h[i] = 0;
        __syncthreads();
        int es = b * PEPB;
        int ee = min(es + PEPB, N_EDGES);
        for (int i = es + t; i < ee; i += 512) atomicAdd(&h[dst[i] >> 8], 1);
        __syncthreads();
        for (int i = t; i < NBUCK; i += 512) {
            int c = h[i];
            base[i] = i * BUCKCAP + (c ? atomicAdd(&cursor[i], c) : 0);
        }
        __syncthreads();
        for (int i = t; i < NBUCK; i += 512) h[i] = 0;
        __syncthreads();
        for (int i = es + t; i < ee; i += 512) {
            int d = dst[i];
            int bk = d >> 8;
            int r = atomicAdd(&h[bk], 1);
            pairs[base[bk] + r] = ((unsigned)src[i] << 8) | (unsigned)(d & 255);
        }
        return;
    }
    b -= PNPART;
    if (b < CASTB) {
        // 8 floats/thread: one pass over x produces BOTH the fp16 and fp8 tables
        int g = b * 512 + t;
        const float4* x4 = (const float4*)x;
        float4 lo = x4[2 * g], hi = x4[2 * g + 1];
        uint4 o;
        o.x = packh(lo.x, lo.y);
        o.y = packh(lo.z, lo.w);
        o.z = packh(hi.x, hi.y);
        o.w = packh(hi.z, hi.w);
        xh[g] = o;
        uint2 o8;
        o8.x = fp8pack(lo.x, lo.y, lo.z, lo.w);
        o8.y = fp8pack(hi.x, hi.y, hi.z, hi.w);
        ((uint2*)xf8)[g] = o8;
        return;
    }
    b -= CASTB;
    {
        int idx = b * 512 + t;
        if (idx < SWZ1_TOTAL) {
            int j = idx & 7, l15 = (idx >> 3) & 15, quad = (idx >> 7) & 3;
            int rem = idx >> 9;
            int c = rem & 7, kt = rem >> 3;
            int k = kt * 32 + quad * 8 + j;
            int n = c * 16 + l15;
            float val = (k < 128) ? Wl1[k * HIDDEN + n] : Wr1[(k - 128) * HIDDEN + n];
            out1[idx] = f2hbits(val);
        } else if (idx < SWZ1_TOTAL + SWZ2_TOTAL) {
            idx -= SWZ1_TOTAL;
            int j = idx & 7, l15 = (idx >> 3) & 15, quad = (idx >> 7) & 3;
            int rem = idx >> 9;
            int c = rem & 7, kt = rem >> 3;
            int k = kt * 32 + quad * 8 + j;
            int n = c * 16 + l15;
            float val = 0.0f;
            if (n < D_OUT) val = Wl2[k * D_OUT + n];
            else if (n >= 64 && n < 64 + D_OUT) val = Wr2[k * D_OUT + (n - 64)];
            out2[idx] = f2hbits(val);
        }
    }
}

// ---------------- per-bucket CSR finalize: count+scan+fill all in LDS ----------------
// sortedSrc entries are PRE-SCALED byte offsets (src<<7: both gather tables have 128B rows).
// Zeroes a 64-entry gap after the bucket fill (clamped to own region) for branch-free tails.
__global__ void csr_kernel(const unsigned* __restrict__ pairs, const int* __restrict__ bcnt,
                           int* __restrict__ hist, int* __restrict__ rowStart,
                           int* __restrict__ sortedSrc) {
    __shared__ int cnt[256];
    __shared__ int sc[256];
    __shared__ int cur[256];
    int b = blockIdx.x, t = threadIdx.x;
    int es = b * BUCKCAP;
    int ee = es + bcnt[b];
    cnt[t] = 0;
    __syncthreads();
    for (int i = es + t; i < ee; i += 256) atomicAdd(&cnt[pairs[i] & 255], 1);
    __syncthreads();
    int v = cnt[t];
    sc[t] = v;
    __syncthreads();
    for (int off = 1; off < 256; off <<= 1) {
        int tmp = (t >= off) ? sc[t - off] : 0;
        __syncthreads();
        sc[t] += tmp;
        __syncthreads();
    }
    int excl = sc[t] - v;
    int node = (b << 8) + t;
    if (node < N_NODES) {
        hist[node] = v;
        rowStart[node] = es + excl;
    }
    cur[t] = excl;
    __syncthreads();
    for (int i = es + t; i < ee; i += 256) {
        unsigned p = pairs[i];
        int r = atomicAdd(&cur[p & 255], 1);
        sortedSrc[es + r] = (int)((p >> 8) << 7);   // pre-scaled byte offset
    }
    // zero the tail-pad gap (no race: clamped to this bucket's own region; last bucket unclamped)
    if (t < 64 && (b == NBUCK - 1 || ee + t < es + BUCKCAP)) sortedSrc[ee + t] = 0;
}

// ---------------- layer-1 gather-mean from fp8 table: one wave per node ----------------
// 4 edge-groups (g) x 16 lanes (sl) x 8 features; float2 accumulators -> v_pk_add_f32.
// sortedSrc holds byte offsets: row addr = base + (off + sl*8), 32-bit voffset.
#define ACC2(v)                                                                   \
    { a[0] += fp8lo(v.x); a[1] += fp8hi(v.x);                                     \
      a[2] += fp8lo(v.y); a[3] += fp8hi(v.y); }

__global__ void agg_kernel(const uint2* __restrict__ xf8,  // [N] 128B fp8 rows
                           const int* __restrict__ sortedSrc,
                           const int* __restrict__ rowStart, const int* __restrict__ hist,
                           uint2* __restrict__ meanh) {
    const char* xb = (const char*)xf8;
    int w = __builtin_amdgcn_readfirstlane((int)(threadIdx.x >> 6));
    int node = blockIdx.x * 4 + w;
    int lane = threadIdx.x & 63;
    int g = lane >> 4, sl = lane & 15;
    unsigned sl8 = (unsigned)(sl * 8);
    int s0 = __builtin_amdgcn_readfirstlane(rowStart[node]);
    int cnt = __builtin_amdgcn_readfirstlane(hist[node]);
    float2v a[4];
#pragma unroll
    for (int e = 0; e < 4; e++) a[e] = (float2v){0.f, 0.f};
    int i = 0;
    for (; i + 16 <= cnt; i += 16) {
        int sA = sortedSrc[s0 + i + g];
        int sB = sortedSrc[s0 + i + 4 + g];
        int sC = sortedSrc[s0 + i + 8 + g];
        int sD = sortedSrc[s0 + i + 12 + g];
        uint2 vA = *(const uint2*)(xb + ((unsigned)sA + sl8));
        uint2 vB = *(const uint2*)(xb + ((unsigned)sB + sl8));
        uint2 vC = *(const uint2*)(xb + ((unsigned)sC + sl8));
        uint2 vD = *(const uint2*)(xb + ((unsigned)sD + sl8));
        ACC2(vA)
        ACC2(vB)
        ACC2(vC)
        ACC2(vD)
    }
    int rem = cnt - i;   // uniform scalar, 0..15
    if (rem) {
        int i0 = s0 + i;
        int sA = sortedSrc[i0 + g];
        int sB = sortedSrc[i0 + 4 + g];
        int sC = sortedSrc[i0 + 8 + g];
        int sD = sortedSrc[i0 + 12 + g];
        uint2 vA = *(const uint2*)(xb + ((unsigned)sA + sl8));
        uint2 vB = *(const uint2*)(xb + ((unsigned)sB + sl8));
        uint2 vC = *(const uint2*)(xb + ((unsigned)sC + sl8));
        uint2 vD = *(const uint2*)(xb + ((unsigned)sD + sl8));
        if (g >= rem)      { vA.x = 0u; vA.y = 0u; }
        if (g + 4 >= rem)  { vB.x = 0u; vB.y = 0u; }
        if (g + 8 >= rem)  { vC.x = 0u; vC.y = 0u; }
        if (g + 12 >= rem) { vD.x = 0u; vD.y = 0u; }
        ACC2(vA)
        ACC2(vB)
        ACC2(vC)
        ACC2(vD)
    }
    // reduce across the 4 edge-groups (lanes xor 16, 32)
#pragma unroll
    for (int e = 0; e < 4; e++) {
        a[e].x += __shfl_xor(a[e].x, 16, 64);
        a[e].y += __shfl_xor(a[e].y, 16, 64);
    }
#pragma unroll
    for (int e = 0; e < 4; e++) {
        a[e].x += __shfl_xor(a[e].x, 32, 64);
        a[e].y += __shfl_xor(a[e].y, 32, 64);
    }
    if (g == 0) {
        float dinv = 1.0f / fmaxf((float)cnt, 1.0f);
        uint2 o;
        o.x = packh(a[0].x * dinv, a[0].y * dinv);
        o.y = packh(a[1].x * dinv, a[1].y * dinv);
        uint2 o2;
        o2.x = packh(a[2].x * dinv, a[2].y * dinv);
        o2.y = packh(a[3].x * dinv, a[3].y * dinv);
        meanh[(size_t)node * 32 + sl * 2] = o;
        meanh[(size_t)node * 32 + sl * 2 + 1] = o2;
    }
}

// ---------------- layer-1 GEMM + norm + relu + layer-2 projection (2 f16 MFMA passes) ----------------
__global__ __launch_bounds__(256) void gemm1g_kernel(
    const unsigned short* __restrict__ meanh, const unsigned short* __restrict__ xh,
    const unsigned short* __restrict__ bswz1, const float* __restrict__ bias1,
    const unsigned short* __restrict__ bswz2,
    unsigned short* __restrict__ g_l, unsigned short* __restrict__ g_r) {
    __shared__ unsigned short hT[4][16][140];
    int tid = threadIdx.x;
    int w = __builtin_amdgcn_readfirstlane(tid >> 6);
    int lane = tid & 63;
    int l15 = lane & 15, quad = lane >> 4;
    int n0 = blockIdx.x * 64;
    int nodeA = n0 + w * 16 + l15;
    if (nodeA >= N_NODES) nodeA = N_NODES - 1;

    float4v acc[8];
#pragma unroll
    for (int c = 0; c < 8; c++) acc[c] = (float4v){0.f, 0.f, 0.f, 0.f};
#pragma unroll
    for (int kt = 0; kt < 8; kt++) {
        const unsigned short* ab = (kt < 4) ? meanh : xh;
        half8 a = *(const half8*)(ab + (size_t)nodeA * 128 + (kt & 3) * 32 + quad * 8);
#pragma unroll
        for (int c = 0; c < 8; c++) {
            half8 b = *(const half8*)(bswz1 + (((kt * 8 + c) * 4 + quad) * 16 + l15) * 8);
            acc[c] = __builtin_amdgcn_mfma_f32_16x16x32_f16(a, b, acc[c], 0, 0, 0);
        }
    }

    float v[8][4];
    float ss[4] = {0.f, 0.f, 0.f, 0.f};
#pragma unroll
    for (int c = 0; c < 8; c++) {
        float bi = bias1[c * 16 + l15];
#pragma unroll
        for (int r = 0; r < 4; r++) {
            float t = acc[c][r] + bi;
            v[c][r] = t;
            ss[r] += t * t;
        }
    }
#pragma unroll
    for (int r = 0; r < 4; r++)
        for (int off = 1; off < 16; off <<= 1) ss[r] += __shfl_xor(ss[r], off, 64);
#pragma unroll
    for (int r = 0; r < 4; r++) {
        float inv = 1.0f / fmaxf(sqrtf(ss[r]), EPSN);
#pragma unroll
        for (int c = 0; c < 8; c++) {
            hT[w][quad * 4 + r][c * 16 + l15] = f2hbits(fmaxf(v[c][r] * inv, 0.0f));
        }
    }

    float4v acc2[8];
#pragma unroll
    for (int c = 0; c < 8; c++) acc2[c] = (float4v){0.f, 0.f, 0.f, 0.f};
#pragma unroll
    for (int kt = 0; kt < 4; kt++) {
        half8 a = *(const half8*)&hT[w][l15][kt * 32 + quad * 8];
#pragma unroll
        for (int c = 0; c < 8; c++) {
            half8 b = *(const half8*)(bswz2 + (((kt * 8 + c) * 4 + quad) * 16 + l15) * 8);
            acc2[c] = __builtin_amdgcn_mfma_f32_16x16x32_f16(a, b, acc2[c], 0, 0, 0);
        }
    }
#pragma unroll
    for (int r = 0; r < 4; r++) {
        int node = n0 + w * 16 + quad * 4 + r;
        if (node < N_NODES) {
#pragma unroll
            for (int c = 0; c < 4; c++)
                g_l[(size_t)node * 64 + c * 16 + l15] = f2hbits(acc2[c][r]);
#pragma unroll
            for (int c = 4; c < 8; c++)
                g_r[(size_t)node * 64 + (c - 4) * 16 + l15] = f2hbits(acc2[c][r]);
        }
    }
}

// ---------------- layer 2 final: 4 nodes per wave, packed fp16 accumulate ----------------
// sortedSrc byte offsets: g_l row addr = base + (off + sl*16), 32-bit voffset.
__global__ void fused2h_kernel(const uint4* __restrict__ g_l4, const uint4* __restrict__ g_r4,
                               const int* __restrict__ sortedSrc,
                               const int* __restrict__ rowStart, const int* __restrict__ hist,
                               const float* __restrict__ bias, float* __restrict__ out) {
    const char* gb = (const char*)g_l4;
    int tid = threadIdx.x;
    int w = __builtin_amdgcn_readfirstlane(tid >> 6);
    int lane = tid & 63;
    int g = lane >> 4, q1 = (lane >> 3) & 1, sl = lane & 7;
    unsigned sl16 = (unsigned)(sl * 16);
    int node = blockIdx.x * 16 + w * 4 + g;   // N_NODES % 16 == 0
    int s0 = rowStart[node];
    int cnt = hist[node];
    H8 A;
    A.u = (uint4){0u, 0u, 0u, 0u};
    int i = 0;
    for (; i + 8 <= cnt; i += 8) {
        int sA = sortedSrc[s0 + i + q1];
        int sB = sortedSrc[s0 + i + 2 + q1];
        int sC = sortedSrc[s0 + i + 4 + q1];
        int sD = sortedSrc[s0 + i + 6 + q1];
        H8 vA, vB, vC, vD;
        vA.u = *(const uint4*)(gb + ((unsigned)sA + sl16));
        vB.u = *(const uint4*)(gb + ((unsigned)sB + sl16));
        vC.u = *(const uint4*)(gb + ((unsigned)sC + sl16));
        vD.u = *(const uint4*)(gb + ((unsigned)sD + sl16));
        A.h += vA.h;
        A.h += vB.h;
        A.h += vC.h;
        A.h += vD.h;
    }
    {
        int rem = cnt - i;   // 0..7
        int i0 = s0 + i;
        int sA = sortedSrc[i0 + q1];
        int sB = sortedSrc[i0 + 2 + q1];
        int sC = sortedSrc[i0 + 4 + q1];
        int sD = sortedSrc[i0 + 6 + q1];
        H8 vA, vB, vC, vD;
        vA.u = *(const uint4*)(gb + ((unsigned)sA + sl16));
        vB.u = *(const uint4*)(gb + ((unsigned)sB + sl16));
        vC.u = *(const uint4*)(gb + ((unsigned)sC + sl16));
        vD.u = *(const uint4*)(gb + ((unsigned)sD + sl16));
        if (q1 >= rem)     vA.u = (uint4){0u, 0u, 0u, 0u};
        if (q1 + 2 >= rem) vB.u = (uint4){0u, 0u, 0u, 0u};
        if (q1 + 4 >= rem) vC.u = (uint4){0u, 0u, 0u, 0u};
        if (q1 + 6 >= rem) vD.u = (uint4){0u, 0u, 0u, 0u};
        A.h += vA.h;
        A.h += vB.h;
        A.h += vC.h;
        A.h += vD.h;
    }
    // reduce across the 2 edge-groups (lanes xor 8) on packed u32
    {
        H8 t1;
        t1.u.x = __shfl_xor(A.u.x, 8, 64);
        t1.u.y = __shfl_xor(A.u.y, 8, 64);
        t1.u.z = __shfl_xor(A.u.z, 8, 64);
        t1.u.w = __shfl_xor(A.u.w, 8, 64);
        A.h += t1.h;
    }
    float a0 = (float)A.h[0], a1 = (float)A.h[1], a2 = (float)A.h[2], a3 = (float)A.h[3];
    float a4 = (float)A.h[4], a5 = (float)A.h[5], a6 = (float)A.h[6], a7 = (float)A.h[7];
    float dinv = 1.0f / fmaxf((float)cnt, 1.0f);
    uint4 gr = g_r4[(size_t)node * 8 + sl];
    bool valid = (sl < 5);
    float b0 = 0, b1 = 0, b2 = 0, b3 = 0, b4 = 0, b5 = 0, b6 = 0, b7 = 0;
    if (valid) {
        b0 = bias[sl * 8 + 0]; b1 = bias[sl * 8 + 1]; b2 = bias[sl * 8 + 2]; b3 = bias[sl * 8 + 3];
        b4 = bias[sl * 8 + 4]; b5 = bias[sl * 8 + 5]; b6 = bias[sl * 8 + 6]; b7 = bias[sl * 8 + 7];
    }
    float t0 = a0 * dinv + hlo(gr.x) + b0;
    float t1 = a1 * dinv + hhi(gr.x) + b1;
    float t2 = a2 * dinv + hlo(gr.y) + b2;
    float t3 = a3 * dinv + hhi(gr.y) + b3;
    float t4 = a4 * dinv + hlo(gr.z) + b4;
    float t5 = a5 * dinv + hhi(gr.z) + b5;
    float t6 = a6 * dinv + hlo(gr.w) + b6;
    float t7 = a7 * dinv + hhi(gr.w) + b7;
    float ssq = t0 * t0 + t1 * t1 + t2 * t2 + t3 * t3 + t4 * t4 + t5 * t5 + t6 * t6 + t7 * t7;
    ssq += __shfl_xor(ssq, 1, 64); ssq += __shfl_xor(ssq, 2, 64); ssq += __shfl_xor(ssq, 4, 64);
    float inv = 1.0f / fmaxf(sqrtf(ssq), EPSN);
    float v0 = t0 * inv, v1 = t1 * inv, v2 = t2 * inv, v3 = t3 * inv;
    float v4 = t4 * inv, v5 = t5 * inv, v6 = t6 * inv, v7 = t7 * inv;
    float m = valid ? fmaxf(fmaxf(fmaxf(v0, v1), fmaxf(v2, v3)),
                            fmaxf(fmaxf(v4, v5), fmaxf(v6, v7))) : -INFINITY;
    m = fmaxf(m, __shfl_xor(m, 1, 64));
    m = fmaxf(m, __shfl_xor(m, 2, 64));
    m = fmaxf(m, __shfl_xor(m, 4, 64));
    float se = 0.0f;
    if (valid) {
        se = expf(v0 - m) + expf(v1 - m) + expf(v2 - m) + expf(v3 - m) +
             expf(v4 - m) + expf(v5 - m) + expf(v6 - m) + expf(v7 - m);
    }
    se += __shfl_xor(se, 1, 64); se += __shfl_xor(se, 2, 64); se += __shfl_xor(se, 4, 64);
    float ls = logf(se) + m;
    if (q1 == 0 && valid) {
        float* o = out + (size_t)node * D_OUT + sl * 8;
        ((float4*)o)[0] = (float4){v0 - ls, v1 - ls, v2 - ls, v3 - ls};
        ((float4*)o)[1] = (float4){v4 - ls, v5 - ls, v6 - ls, v7 - ls};
    }
}

static inline size_t align256(size_t x) { return (x + 255) & ~(size_t)255; }

extern "C" void kernel_launch(void* const* d_in, const int* in_sizes, int n_in,
                              void* d_out, int out_size, void* d_ws, size_t ws_size,
                              hipStream_t stream) {
    const float* x   = (const float*)d_in[0];
    const int*   ei  = (const int*)d_in[1];
    const float* Wl1 = (const float*)d_in[2];
    const float* bl1 = (const float*)d_in[3];
    const float* Wr1 = (const float*)d_in[4];
    const float* Wl2 = (const float*)d_in[5];
    const float* bl2 = (const float*)d_in[6];
    const float* Wr2 = (const float*)d_in[7];
    float* out = (float*)d_out;

    const int* src = ei;
    const int* dst = ei + N_EDGES;

    char* ws = (char*)d_ws;
    size_t off = 0;
    int* cursor      = (int*)(ws + off); off += align256((size_t)NBUCK * 4);
    int* hist        = (int*)(ws + off); off += align256((size_t)N_NODES * 4);
    int* rowStart    = (int*)(ws + off); off += align256((size_t)N_NODES * 4);
    unsigned* pairs  = (unsigned*)(ws + off); off += align256((size_t)NBUCK * BUCKCAP * 4);
    int* sortedSrc   = (int*)(ws + off); off += align256(((size_t)NBUCK * BUCKCAP + 64) * 4);
    unsigned* xh     = (unsigned*)(ws + off); off += align256((size_t)N_NODES * 128 * 2);
    unsigned* xf8    = (unsigned*)(ws + off); off += align256((size_t)N_NODES * 128);
    unsigned* meanh  = (unsigned*)(ws + off); off += align256((size_t)N_NODES * 128 * 2);
    unsigned short* g_l = (unsigned short*)(ws + off); off += align256((size_t)N_NODES * 64 * 2);
    unsigned short* g_r = (unsigned short*)(ws + off); off += align256((size_t)N_NODES * 64 * 2);
    unsigned short* bswz1 = (unsigned short*)(ws + off); off += align256((size_t)SWZ1_TOTAL * 2);
    unsigned short* bswz2 = (unsigned short*)(ws + off); off += align256((size_t)SWZ2_TOTAL * 2);

    hipMemsetAsync(cursor, 0, (size_t)NBUCK * 4, stream);

    prep_bpart_kernel<<<PNPART + CASTB + SWZB, 512, 0, stream>>>(
        src, dst, cursor, pairs,
        x, (uint4*)xh, xf8, Wl1, Wr1, Wl2, Wr2, bswz1, bswz2);
    csr_kernel<<<NBUCK, 256, 0, stream>>>(pairs, cursor, hist, rowStart, sortedSrc);

    agg_kernel<<<N_NODES / 4, 256, 0, stream>>>((const uint2*)xf8, sortedSrc, rowStart, hist,
                                                (uint2*)meanh);
    gemm1g_kernel<<<(N_NODES + 63) / 64, 256, 0, stream>>>(
        (const unsigned short*)meanh, (const unsigned short*)xh,
        bswz1, bl1, bswz2, g_l, g_r);
    fused2h_kernel<<<N_NODES / 16, 256, 0, stream>>>(
        (const uint4*)g_l, (const uint4*)g_r, sortedSrc, rowStart, hist, bl2, out);
}